// Round 14
// baseline (187.359 us; speedup 1.0000x reference)
//
#include <hip/hip_runtime.h>

#define B_ROWS  16384
#define IN_DIM  1024
#define NEXP    8
#define HID     128
#define NCLS    1024
#define NPAIR   56
#define MAXW1   520   // max K1 work items: 32768/64 + 8
#define MAXW2   312   // max K2 work items: 16384/64 + 56

#define GATE_BLOCKS (B_ROWS / 8)                        // 2048
#define W1T_BLOCKS  (NEXP * (IN_DIM / 32) * (HID / 32)) // 1024
#define W2T_BLOCKS  (NEXP * (HID / 32) * (NCLS / 32))   // 1024

typedef __attribute__((ext_vector_type(8))) short bf16x8;
typedef __attribute__((ext_vector_type(4))) float f32x4;
typedef __attribute__((ext_vector_type(4))) unsigned int u32x4;
typedef __attribute__((ext_vector_type(8))) unsigned short u16x8;

__device__ __forceinline__ unsigned short f2bf(float f) {
  union { float f; unsigned u; } v; v.f = f;
  unsigned r = v.u + 0x7FFFu + ((v.u >> 16) & 1u);
  return (unsigned short)(r >> 16);
}

// XOR-swizzled LDS addressing (T2): linear rows, 8-short (16B) slots,
// slot ^= row&7.
__device__ __forceinline__ int sw64(int row, int sh) {   // 64-short rows
  return (row << 6) + ((((sh >> 3) ^ row) & 7) << 3) + (sh & 7);
}
__device__ __forceinline__ int sw256(int row, int sh) {  // 256-short rows
  return (row << 8) + ((((sh >> 3) ^ row) & 7) << 3) + (sh & 7) + ((sh >> 6) << 6);
}

// ---------------------------------------------------------------------------
// Fused prep: blocks [0,2048) gate + x->bf16 + LDS hist/psum (absorbs the
// old hist_part kernel); [2048,3072) w1 transpose; [3072,4096) w2 transpose.
// ---------------------------------------------------------------------------
__global__ __launch_bounds__(256) void prep_kernel(
    const float* __restrict__ x, const float* __restrict__ gw,
    const float* __restrict__ gb, const float* __restrict__ w1,
    const float* __restrict__ w2, unsigned short* __restrict__ xb,
    unsigned short* __restrict__ w1bt, unsigned short* __restrict__ w2bt,
    float2* __restrict__ tval, unsigned char* __restrict__ pairid,
    int* __restrict__ partials, float2* __restrict__ psum) {
  __shared__ __attribute__((aligned(16))) unsigned char pmem[NEXP * IN_DIM * 4];
  __shared__ int hh[64];
  __shared__ float ps[8];
  const int bid = blockIdx.x;
  const int t = threadIdx.x;

  if (bid < GATE_BLOCKS) {
    float (*gws)[IN_DIM] = (float(*)[IN_DIM])pmem;   // 32 KB
#pragma unroll
    for (int kk = 0; kk < 4; ++kk) {
      const int k = kk * 256 + t;
      const float4 g0 = *(const float4*)(gw + k * NEXP);
      const float4 g1 = *(const float4*)(gw + k * NEXP + 4);
      gws[0][k] = g0.x; gws[1][k] = g0.y; gws[2][k] = g0.z; gws[3][k] = g0.w;
      gws[4][k] = g1.x; gws[5][k] = g1.y; gws[6][k] = g1.z; gws[7][k] = g1.w;
    }
    if (t < 64) hh[t] = 0;
    __syncthreads();

    const int wave = t >> 6, l = t & 63;
    const int r0 = bid * 8 + wave * 2;

    float4 xv0[4], xv1[4];
#pragma unroll
    for (int j = 0; j < 4; ++j) {
      xv0[j] = *(const float4*)(x + (size_t)r0 * IN_DIM + j * 256 + l * 4);
      xv1[j] = *(const float4*)(x + (size_t)(r0 + 1) * IN_DIM + j * 256 + l * 4);
    }

    if (xb) {
#pragma unroll
      for (int j = 0; j < 4; ++j) {
        uint2 p0, p1;
        p0.x = (unsigned)f2bf(xv0[j].x) | ((unsigned)f2bf(xv0[j].y) << 16);
        p0.y = (unsigned)f2bf(xv0[j].z) | ((unsigned)f2bf(xv0[j].w) << 16);
        p1.x = (unsigned)f2bf(xv1[j].x) | ((unsigned)f2bf(xv1[j].y) << 16);
        p1.y = (unsigned)f2bf(xv1[j].z) | ((unsigned)f2bf(xv1[j].w) << 16);
        *(uint2*)(xb + (size_t)r0 * IN_DIM + j * 256 + l * 4)       = p0;
        *(uint2*)(xb + (size_t)(r0 + 1) * IN_DIM + j * 256 + l * 4) = p1;
      }
    }

    float a0[NEXP], a1[NEXP];
#pragma unroll
    for (int e = 0; e < NEXP; ++e) { a0[e] = 0.f; a1[e] = 0.f; }
#pragma unroll
    for (int e = 0; e < NEXP; ++e) {
#pragma unroll
      for (int j = 0; j < 4; ++j) {
        const float4 g = *(const float4*)&gws[e][j * 256 + l * 4];
        a0[e] = fmaf(xv0[j].x, g.x, a0[e]); a0[e] = fmaf(xv0[j].y, g.y, a0[e]);
        a0[e] = fmaf(xv0[j].z, g.z, a0[e]); a0[e] = fmaf(xv0[j].w, g.w, a0[e]);
        a1[e] = fmaf(xv1[j].x, g.x, a1[e]); a1[e] = fmaf(xv1[j].y, g.y, a1[e]);
        a1[e] = fmaf(xv1[j].z, g.z, a1[e]); a1[e] = fmaf(xv1[j].w, g.w, a1[e]);
      }
    }
#pragma unroll
    for (int e = 0; e < NEXP; ++e) {
#pragma unroll
      for (int off = 32; off > 0; off >>= 1) {
        a0[e] += __shfl_xor(a0[e], off);
        a1[e] += __shfl_xor(a1[e], off);
      }
    }

    if (l == 0) {
      float sv0 = 0.f, sv1 = 0.f;
#pragma unroll
      for (int rr = 0; rr < 2; ++rr) {
        const float* a = rr ? a1 : a0;
        float lg[NEXP];
#pragma unroll
        for (int e = 0; e < NEXP; ++e) lg[e] = a[e] + gb[e];
        float m = lg[0];
#pragma unroll
        for (int e = 1; e < NEXP; ++e) m = fmaxf(m, lg[e]);
        float p[NEXP], s = 0.f;
#pragma unroll
        for (int e = 0; e < NEXP; ++e) { p[e] = __expf(lg[e] - m); s += p[e]; }
        const float inv = 1.f / s;
        int   i0 = 0;  float v0 = p[0];
#pragma unroll
        for (int e = 1; e < NEXP; ++e) if (p[e] > v0) { v0 = p[e]; i0 = e; }
        int   i1 = -1; float v1 = -1.f;
#pragma unroll
        for (int e = 0; e < NEXP; ++e)
          if (e != i0 && p[e] > v1) { v1 = p[e]; i1 = e; }
        tval[r0 + rr] = make_float2(v0 * inv, v1 * inv);
        const int pr = i0 * 7 + i1 - (i1 > i0 ? 1 : 0);
        pairid[r0 + rr] = (unsigned char)pr;
        sv0 += v0 * inv; sv1 += v1 * inv;
        atomicAdd(&hh[pr], 1);
        atomicAdd(&hh[56 + i0], 1);
        atomicAdd(&hh[56 + i1], 1);
      }
      ps[wave * 2]     = sv0;
      ps[wave * 2 + 1] = sv1;
    }
    __syncthreads();
    if (t < 64) partials[(size_t)bid * 64 + t] = hh[t];
    if (t == 0)
      psum[bid] = make_float2(ps[0] + ps[2] + ps[4] + ps[6],
                              ps[1] + ps[3] + ps[5] + ps[7]);
  } else {
    float (*tile)[33] = (float(*)[33])pmem;
    const float* src; unsigned short* dst;
    int R, C, r0, c0, e;
    if (bid < GATE_BLOCKS + W1T_BLOCKS) {
      const int b1 = bid - GATE_BLOCKS;
      e = b1 >> 7; const int rem = b1 & 127;
      R = IN_DIM; C = HID;
      c0 = (rem & 3) * 32; r0 = (rem >> 2) * 32;
      src = w1; dst = w1bt;
    } else {
      const int b2 = bid - GATE_BLOCKS - W1T_BLOCKS;
      e = b2 >> 7; const int rem = b2 & 127;
      R = HID; C = NCLS;
      c0 = (rem & 31) * 32; r0 = (rem >> 5) * 32;
      src = w2; dst = w2bt;
    }
    src += (size_t)e * R * C;
    dst += (size_t)e * R * C;
    const int tx = t & 31, ty = t >> 5;
#pragma unroll
    for (int i = ty; i < 32; i += 8)
      tile[i][tx] = src[(size_t)(r0 + i) * C + c0 + tx];
    __syncthreads();
#pragma unroll
    for (int i = ty; i < 32; i += 8)
      dst[(size_t)(c0 + i) * R + r0 + tx] = f2bf(tile[tx][i]);
  }
}

// ---------------------------------------------------------------------------
// Scan (256 threads): parallel-sum partials -> hist; psum -> gates output;
// thread 0 builds exclusive bases, cursors, exact work lists.
// ---------------------------------------------------------------------------
__global__ __launch_bounds__(256) void scan_kernel(
    const int* __restrict__ partials, const float2* __restrict__ psum,
    int* __restrict__ hist, int* __restrict__ base, int* __restrict__ csr,
    int* __restrict__ meta, float* __restrict__ out) {
  const int t = threadIdx.x;
  __shared__ int hpart[256];
  __shared__ float r0a[256], r1a[256];
  __shared__ float gg[2];

  // hist: bin = t&63, chunk = t>>6 covers GATE_BLOCKS/4 blocks
  {
    const int bin = t & 63, ch = t >> 6;
    int s = 0;
    for (int b = ch; b < GATE_BLOCKS; b += 4) s += partials[(size_t)b * 64 + bin];
    hpart[t] = s;
  }
  // psum: strided partial sums
  {
    float g0 = 0.f, g1 = 0.f;
    for (int b = t; b < GATE_BLOCKS; b += 256) { g0 += psum[b].x; g1 += psum[b].y; }
    r0a[t] = g0; r1a[t] = g1;
  }
  __syncthreads();
  if (t < 64)
    hist[t] = hpart[t] + hpart[64 + t] + hpart[128 + t] + hpart[192 + t];
#pragma unroll
  for (int s = 128; s > 0; s >>= 1) {
    if (t < s) { r0a[t] += r0a[t + s]; r1a[t] += r1a[t + s]; }
    __syncthreads();
  }
  if (t == 0) { gg[0] = r0a[0]; gg[1] = r1a[0]; }
  __syncthreads();

  float* gout = out + (size_t)B_ROWS * NCLS;
  for (int c = t; c < NCLS; c += 256) {
    gout[c]        = gg[0];
    gout[NCLS + c] = gg[1];
  }
  if (t != 0) return;
  int accp = 0, acce = 0;
  for (int p = 0; p < NPAIR; ++p) { base[p] = accp; csr[p] = accp; accp += hist[p]; }
  for (int e = 0; e < NEXP; ++e) {
    base[56 + e] = acce; csr[56 + e] = acce; acce += hist[56 + e];
  }
  int n = 0;
  int* w1 = meta + 2;
  for (int e = 0; e < NEXP; ++e) {
    const int tiles = (hist[56 + e] + 63) >> 6;
    for (int i = 0; i < tiles; ++i) w1[n++] = (e << 16) | i;
  }
  meta[0] = n;
  n = 0;
  int* w2 = meta + 2 + MAXW1;
  for (int p = 0; p < NPAIR; ++p) {
    const int tiles = (hist[p] + 63) >> 6;
    for (int i = 0; i < tiles; ++i) w2[n++] = (p << 16) | i;
  }
  meta[1] = n;
}

// ---------------------------------------------------------------------------
// Scatter: per-block LDS histogram -> one aggregated atomic per bin per block.
// elist entry = (pp << 15) | (row << 1) | slot  (pp = plist position).
// ---------------------------------------------------------------------------
__global__ __launch_bounds__(256) void scatter_kernel(
    const unsigned char* __restrict__ pairid, int* __restrict__ csr,
    int* __restrict__ elist, int* __restrict__ plist) {
  __shared__ int h[64], lbase[64];
  const int t = threadIdx.x;
  if (t < 64) h[t] = 0;
  __syncthreads();
  const int row = blockIdx.x * 256 + t;
  const int p  = pairid[row];
  const int ea = p / 7, rem = p % 7;
  const int eb = rem + (rem >= ea ? 1 : 0);
  const int op = atomicAdd(&h[p], 1);
  const int oa = atomicAdd(&h[56 + ea], 1);
  const int ob = atomicAdd(&h[56 + eb], 1);
  __syncthreads();
  if (t < 64) lbase[t] = h[t] ? atomicAdd(&csr[t], h[t]) : 0;
  __syncthreads();
  const int pp = lbase[p] + op;                   // plist position
  plist[pp] = row;
  elist[lbase[56 + ea] + oa] = (pp << 15) | (row << 1);
  elist[lbase[56 + eb] + ob] = (pp << 15) | (row << 1) | 1;
}

// ---------------------------------------------------------------------------
// K1: hidden GEMM, expert-grouped. Writes Hg in PLIST ORDER (index pp from
// the packed elist entry) so k2's A-tile read is sequential.
// ---------------------------------------------------------------------------
template <bool XB>
__global__ __launch_bounds__(256) void k1_hidden(
    const float* __restrict__ x, const unsigned short* __restrict__ xb,
    const unsigned short* __restrict__ w1bt, const float* __restrict__ b1,
    const float2* __restrict__ tval, const int* __restrict__ elist,
    const int* __restrict__ hist, const int* __restrict__ base,
    const int* __restrict__ meta, unsigned short* __restrict__ Hg) {
  const int b = blockIdx.x;
  if (b >= meta[0]) return;
  const int item = meta[2 + b];
  const int e = item >> 16, tile = item & 0xffff;
  const int start = tile * 64;
  const int nr = min(64, hist[56 + e] - start);

  __shared__ unsigned short As[64 * 64];
  __shared__ unsigned short Bs[128 * 64];
  __shared__ int rowl[64];

  const int t = threadIdx.x;
  if (t < 64) rowl[t] = elist[base[56 + e] + start + (t < nr ? t : 0)];
  __syncthreads();

  const int wid = t >> 6, l = t & 63;
  const int wr = wid >> 1, wc = wid & 1;
  const int lg = l >> 4,   ln = l & 15;

  f32x4 acc[2][4];
#pragma unroll
  for (int ms = 0; ms < 2; ++ms)
#pragma unroll
    for (int nf = 0; nf < 4; ++nf) acc[ms][nf] = (f32x4){0.f, 0.f, 0.f, 0.f};

  const int ai = t >> 2, aseg = t & 3;
  const int arow = (rowl[ai] >> 1) & 0x3FFF;
  const float* asrcf = x + (size_t)arow * IN_DIM + aseg * 16;
  const unsigned short* asrcb = xb + (size_t)arow * IN_DIM + aseg * 16;
  const int bn = t >> 1, bhf = t & 1;
  const unsigned short* bsrc =
      w1bt + ((size_t)e * HID + bn) * IN_DIM + bhf * 32;

  if constexpr (XB) {
    u32x4 areg[2], breg[4];
    {
      const u32x4* ap = (const u32x4*)(asrcb);
      areg[0] = ap[0]; areg[1] = ap[1];
      const u32x4* bp = (const u32x4*)(bsrc);
#pragma unroll
      for (int j = 0; j < 4; ++j) breg[j] = bp[j];
    }
    for (int ks = 0; ks < 16; ++ks) {
      *(u32x4*)&As[sw64(ai, aseg * 16)]     = areg[0];
      *(u32x4*)&As[sw64(ai, aseg * 16 + 8)] = areg[1];
#pragma unroll
      for (int j = 0; j < 4; ++j)
        *(u32x4*)&Bs[sw64(bn, bhf * 32 + j * 8)] = breg[j];
      __syncthreads();
      if (ks < 15) {
        const u32x4* ap = (const u32x4*)(asrcb + (ks + 1) * 64);
        areg[0] = ap[0]; areg[1] = ap[1];
        const u32x4* bp = (const u32x4*)(bsrc + (ks + 1) * 64);
#pragma unroll
        for (int j = 0; j < 4; ++j) breg[j] = bp[j];
      }
      bf16x8 af[2][2], bf[4][2];
#pragma unroll
      for (int ms = 0; ms < 2; ++ms)
#pragma unroll
        for (int kh = 0; kh < 2; ++kh)
          af[ms][kh] = *(const bf16x8*)&As[sw64(wr*32 + ms*16 + ln, kh*32 + lg*8)];
#pragma unroll
      for (int nf = 0; nf < 4; ++nf)
#pragma unroll
        for (int kh = 0; kh < 2; ++kh)
          bf[nf][kh] = *(const bf16x8*)&Bs[sw64(wc*64 + nf*16 + ln, kh*32 + lg*8)];
#pragma unroll
      for (int ms = 0; ms < 2; ++ms)
#pragma unroll
        for (int nf = 0; nf < 4; ++nf) {
          acc[ms][nf] = __builtin_amdgcn_mfma_f32_16x16x32_bf16(af[ms][0], bf[nf][0], acc[ms][nf], 0, 0, 0);
          acc[ms][nf] = __builtin_amdgcn_mfma_f32_16x16x32_bf16(af[ms][1], bf[nf][1], acc[ms][nf], 0, 0, 0);
        }
      __syncthreads();
    }
  } else {
    for (int ks = 0; ks < 16; ++ks) {
      {
        const float4 f0 = *(const float4*)(asrcf + ks * 64);
        const float4 f1 = *(const float4*)(asrcf + ks * 64 + 4);
        const float4 f2 = *(const float4*)(asrcf + ks * 64 + 8);
        const float4 f3 = *(const float4*)(asrcf + ks * 64 + 12);
        u16x8 u0, u1;
        u0[0]=f2bf(f0.x); u0[1]=f2bf(f0.y); u0[2]=f2bf(f0.z); u0[3]=f2bf(f0.w);
        u0[4]=f2bf(f1.x); u0[5]=f2bf(f1.y); u0[6]=f2bf(f1.z); u0[7]=f2bf(f1.w);
        u1[0]=f2bf(f2.x); u1[1]=f2bf(f2.y); u1[2]=f2bf(f2.z); u1[3]=f2bf(f2.w);
        u1[4]=f2bf(f3.x); u1[5]=f2bf(f3.y); u1[6]=f2bf(f3.z); u1[7]=f2bf(f3.w);
        *(u16x8*)&As[sw64(ai, aseg * 16)]     = u0;
        *(u16x8*)&As[sw64(ai, aseg * 16 + 8)] = u1;
      }
      {
        const u32x4* bp = (const u32x4*)(bsrc + ks * 64);
#pragma unroll
        for (int j = 0; j < 4; ++j)
          *(u32x4*)&Bs[sw64(bn, bhf * 32 + j * 8)] = bp[j];
      }
      __syncthreads();
      bf16x8 af[2][2], bf[4][2];
#pragma unroll
      for (int ms = 0; ms < 2; ++ms)
#pragma unroll
        for (int kh = 0; kh < 2; ++kh)
          af[ms][kh] = *(const bf16x8*)&As[sw64(wr*32 + ms*16 + ln, kh*32 + lg*8)];
#pragma unroll
      for (int nf = 0; nf < 4; ++nf)
#pragma unroll
        for (int kh = 0; kh < 2; ++kh)
          bf[nf][kh] = *(const bf16x8*)&Bs[sw64(wc*64 + nf*16 + ln, kh*32 + lg*8)];
#pragma unroll
      for (int ms = 0; ms < 2; ++ms)
#pragma unroll
        for (int nf = 0; nf < 4; ++nf) {
          acc[ms][nf] = __builtin_amdgcn_mfma_f32_16x16x32_bf16(af[ms][0], bf[nf][0], acc[ms][nf], 0, 0, 0);
          acc[ms][nf] = __builtin_amdgcn_mfma_f32_16x16x32_bf16(af[ms][1], bf[nf][1], acc[ms][nf], 0, 0, 0);
        }
      __syncthreads();
    }
  }

  float b1c[4];
#pragma unroll
  for (int nf = 0; nf < 4; ++nf) b1c[nf] = b1[e * HID + wc*64 + nf*16 + ln];

#pragma unroll
  for (int ms = 0; ms < 2; ++ms)
#pragma unroll
    for (int r = 0; r < 4; ++r) {
      const int li = wr*32 + ms*16 + lg*4 + r;
      if (li < nr) {
        const int packed = rowl[li];
        const int row  = (packed >> 1) & 0x3FFF;
        const int slot = packed & 1;
        const int pp   = ((unsigned)packed) >> 15;
        const float2 tv = tval[row];
        const float vv = slot ? tv.y : tv.x;
#pragma unroll
        for (int nf = 0; nf < 4; ++nf) {
          const float hh = fmaxf(acc[ms][nf][r] + b1c[nf], 0.f) * vv;
          Hg[((size_t)pp * 2 + slot) * HID + wc*64 + nf*16 + ln] = f2bf(hh);
        }
      }
    }
}

// ---------------------------------------------------------------------------
// K2: output GEMM, pair-grouped. Two c-halves per block: the sequential
// 32 KB Ah stage is amortized over 256 output columns (Hg re-staging 8x->4x)
// while keeping the round-8 register budget (acc[2][4] per half).
// ---------------------------------------------------------------------------
__global__ __launch_bounds__(256) void k2_out(
    const unsigned short* __restrict__ Hg, const unsigned short* __restrict__ w2bt,
    const float* __restrict__ b2, const float2* __restrict__ tval,
    const int* __restrict__ plist, const int* __restrict__ hist,
    const int* __restrict__ base, const int* __restrict__ meta,
    float* __restrict__ out) {
  const int b = blockIdx.y;
  if (b >= meta[1]) return;
  const int item = meta[2 + MAXW1 + b];
  const int p = item >> 16, rt = item & 0xffff;
  const int ea = p / 7, rem = p % 7;
  const int eb = rem + (rem >= ea ? 1 : 0);
  const int start = rt * 64;
  const int gpos = base[p] + start;          // plist-global row-tile start
  const int nr = min(64, hist[p] - start);
  const int c0base = blockIdx.x * 256;

  __shared__ unsigned short Ah[64 * 256];   // 32 KB, staged once (sequential)
  __shared__ unsigned short Bs[128 * 64];   // 16 KB, per-ks
  __shared__ int rowl[64];
  __shared__ float2 vals[64];

  const int t = threadIdx.x;
  if (t < 64) {
    const int r = plist[gpos + (t < nr ? t : 0)];
    rowl[t] = r;
    vals[t] = tval[r];
  }
  __syncthreads();

  // stage A: rows gpos..gpos+63 of plist-ordered Hg -> contiguous 32 KB
  {
    const int i = t >> 2, q = t & 3;
    const int srow = min(gpos + i, B_ROWS - 1);   // clamp tail padding
    const u32x4* src = (const u32x4*)(Hg + (size_t)srow * 256 + q * 64);
#pragma unroll
    for (int j = 0; j < 8; ++j)
      *(u32x4*)&Ah[sw256(i, q * 64 + j * 8)] = src[j];
  }

  const int wid = t >> 6, l = t & 63;
  const int wr = wid >> 1, wc = wid & 1;
  const int lg = l >> 4,   ln = l & 15;
  const int bn = t >> 1, bhf = t & 1;

#pragma unroll
  for (int ch2 = 0; ch2 < 2; ++ch2) {
    const int c0 = c0base + ch2 * 128;

    f32x4 acc[2][4];
#pragma unroll
    for (int ms = 0; ms < 2; ++ms)
#pragma unroll
      for (int nf = 0; nf < 4; ++nf) acc[ms][nf] = (f32x4){0.f, 0.f, 0.f, 0.f};

    u32x4 breg[4];
    {
      const u32x4* bp = (const u32x4*)(
          w2bt + ((size_t)ea * NCLS + c0 + bn) * HID + bhf * 32);
#pragma unroll
      for (int j = 0; j < 4; ++j) breg[j] = bp[j];
    }
#pragma unroll
    for (int ks = 0; ks < 4; ++ks) {
#pragma unroll
      for (int j = 0; j < 4; ++j)
        *(u32x4*)&Bs[sw64(bn, bhf * 32 + j * 8)] = breg[j];
      __syncthreads();
      if (ks < 3) {   // prefetch next ks; hides under ds_read+MFMA
        const int exn = (ks + 1 < 2) ? ea : eb;
        const int hbn = ((ks + 1) & 1) * 64;
        const u32x4* bp = (const u32x4*)(
            w2bt + ((size_t)exn * NCLS + c0 + bn) * HID + hbn + bhf * 32);
#pragma unroll
        for (int j = 0; j < 4; ++j) breg[j] = bp[j];
      }
      bf16x8 af[2][2], bf[4][2];
#pragma unroll
      for (int ms = 0; ms < 2; ++ms)
#pragma unroll
        for (int kh = 0; kh < 2; ++kh)
          af[ms][kh] = *(const bf16x8*)&Ah[sw256(wr*32 + ms*16 + ln, ks*64 + kh*32 + lg*8)];
#pragma unroll
      for (int nf = 0; nf < 4; ++nf)
#pragma unroll
        for (int kh = 0; kh < 2; ++kh)
          bf[nf][kh] = *(const bf16x8*)&Bs[sw64(wc*64 + nf*16 + ln, kh*32 + lg*8)];
#pragma unroll
      for (int ms = 0; ms < 2; ++ms)
#pragma unroll
        for (int nf = 0; nf < 4; ++nf) {
          acc[ms][nf] = __builtin_amdgcn_mfma_f32_16x16x32_bf16(af[ms][0], bf[nf][0], acc[ms][nf], 0, 0, 0);
          acc[ms][nf] = __builtin_amdgcn_mfma_f32_16x16x32_bf16(af[ms][1], bf[nf][1], acc[ms][nf], 0, 0, 0);
        }
      __syncthreads();
    }

    float b2a[4], b2b[4];
#pragma unroll
    for (int nf = 0; nf < 4; ++nf) {
      const int c = c0 + wc*64 + nf*16 + ln;
      b2a[nf] = b2[ea * NCLS + c];
      b2b[nf] = b2[eb * NCLS + c];
    }
#pragma unroll
    for (int ms = 0; ms < 2; ++ms)
#pragma unroll
      for (int r = 0; r < 4; ++r) {
        const int li = wr*32 + ms*16 + lg*4 + r;
        if (li < nr) {
          const int row = rowl[li];
          const float2 v = vals[li];
#pragma unroll
          for (int nf = 0; nf < 4; ++nf) {
            const int c = c0 + wc*64 + nf*16 + ln;
            out[(size_t)row * NCLS + c] = acc[ms][nf][r] + v.x * b2a[nf] + v.y * b2b[nf];
          }
        }
      }
  }
}

extern "C" void kernel_launch(void* const* d_in, const int* in_sizes, int n_in,
                              void* d_out, int out_size, void* d_ws, size_t ws_size,
                              hipStream_t stream) {
  const float* x   = (const float*)d_in[0];
  const float* gw  = (const float*)d_in[1];
  const float* gb  = (const float*)d_in[2];
  const float* w1  = (const float*)d_in[3];
  const float* b1  = (const float*)d_in[4];
  const float* w2  = (const float*)d_in[5];
  const float* b2  = (const float*)d_in[6];
  float* out = (float*)d_out;

  // ws layout (bytes). Nothing needs pre-zeroing:
  //   hist 0..256 | base 256..512 | csr 512..768 | meta 768..4104 (pad 4352)
  //   partials 4352..528640 (2048*64 int) | psum 528640..545024
  //   pairid 545024..561408 | tval 561408..692480
  //   elist 692480..823552 | plist 823552..889088
  //   w1bt 889088..2986240 | w2bt 2986240..5083392 | Hg 5083392..13472000
  //   xb  13472000..47026432 (optional)
  char* ws = (char*)d_ws;
  int*            hist     = (int*)(ws);
  int*            base     = (int*)(ws + 256);
  int*            csr      = (int*)(ws + 512);
  int*            meta     = (int*)(ws + 768);
  int*            partials = (int*)(ws + 4352);
  float2*         psum     = (float2*)(ws + 528640);
  unsigned char*  pairid   = (unsigned char*)(ws + 545024);
  float2*         tval     = (float2*)(ws + 561408);
  int*            elist    = (int*)(ws + 692480);
  int*            plist    = (int*)(ws + 823552);
  unsigned short* w1bt     = (unsigned short*)(ws + 889088);
  unsigned short* w2bt     = (unsigned short*)(ws + 2986240);
  unsigned short* Hg       = (unsigned short*)(ws + 5083392);
  const bool use_xb = (ws_size >= (size_t)47026432);
  unsigned short* xb = use_xb ? (unsigned short*)(ws + 13472000) : nullptr;

  prep_kernel<<<GATE_BLOCKS + W1T_BLOCKS + W2T_BLOCKS, 256, 0, stream>>>(
      x, gw, gb, w1, w2, xb, w1bt, w2bt, tval, pairid, partials, psum);
  scan_kernel<<<1, 256, 0, stream>>>(partials, psum, hist, base, csr, meta, out);
  scatter_kernel<<<B_ROWS / 256, 256, 0, stream>>>(pairid, csr, elist, plist);

  if (use_xb)
    k1_hidden<true><<<MAXW1, 256, 0, stream>>>(x, xb, w1bt, b1, tval, elist,
                                               hist, base, meta, Hg);
  else
    k1_hidden<false><<<MAXW1, 256, 0, stream>>>(x, xb, w1bt, b1, tval, elist,
                                                hist, base, meta, Hg);
  k2_out<<<dim3(NCLS / 256, MAXW2), 256, 0, stream>>>(Hg, w2bt, b2, tval, plist,
                                                      hist, base, meta, out);
}

// Round 15
// 126.813 us; speedup vs baseline: 1.4774x; 1.4774x over previous
//
#include <hip/hip_runtime.h>

#define B_ROWS  16384
#define IN_DIM  1024
#define NEXP    8
#define HID     128
#define NCLS    1024
#define NPAIR   56
#define MAXW1   520   // max K1 work items: 32768/64 + 8
#define MAXW2   312   // max K2 work items: 16384/64 + 56

#define GATE_BLOCKS (B_ROWS / 8)                        // 2048
#define W1T_BLOCKS  (NEXP * (IN_DIM / 32) * (HID / 32)) // 1024
#define W2T_BLOCKS  (NEXP * (HID / 32) * (NCLS / 32))   // 1024

typedef __attribute__((ext_vector_type(8))) short bf16x8;
typedef __attribute__((ext_vector_type(4))) float f32x4;
typedef __attribute__((ext_vector_type(4))) unsigned int u32x4;
typedef __attribute__((ext_vector_type(8))) unsigned short u16x8;

__device__ __forceinline__ unsigned short f2bf(float f) {
  union { float f; unsigned u; } v; v.f = f;
  unsigned r = v.u + 0x7FFFu + ((v.u >> 16) & 1u);
  return (unsigned short)(r >> 16);
}

// XOR-swizzled LDS addressing (T2): linear rows, 8-short (16B) slots,
// slot ^= row&7.
__device__ __forceinline__ int sw64(int row, int sh) {   // 64-short rows
  return (row << 6) + ((((sh >> 3) ^ row) & 7) << 3) + (sh & 7);
}
__device__ __forceinline__ int sw256(int row, int sh) {  // 256-short rows
  return (row << 8) + ((((sh >> 3) ^ row) & 7) << 3) + (sh & 7) + ((sh >> 6) << 6);
}

// ---------------------------------------------------------------------------
// Fused prep: blocks [0,2048) gate + x->bf16 + LDS hist/psum; [2048,3072)
// w1 transpose; [3072,4096) w2 transpose.
// ---------------------------------------------------------------------------
__global__ __launch_bounds__(256) void prep_kernel(
    const float* __restrict__ x, const float* __restrict__ gw,
    const float* __restrict__ gb, const float* __restrict__ w1,
    const float* __restrict__ w2, unsigned short* __restrict__ xb,
    unsigned short* __restrict__ w1bt, unsigned short* __restrict__ w2bt,
    float2* __restrict__ tval, unsigned char* __restrict__ pairid,
    int* __restrict__ partials, float2* __restrict__ psum) {
  __shared__ __attribute__((aligned(16))) unsigned char pmem[NEXP * IN_DIM * 4];
  __shared__ int hh[64];
  __shared__ float ps[8];
  const int bid = blockIdx.x;
  const int t = threadIdx.x;

  if (bid < GATE_BLOCKS) {
    float (*gws)[IN_DIM] = (float(*)[IN_DIM])pmem;   // 32 KB
#pragma unroll
    for (int kk = 0; kk < 4; ++kk) {
      const int k = kk * 256 + t;
      const float4 g0 = *(const float4*)(gw + k * NEXP);
      const float4 g1 = *(const float4*)(gw + k * NEXP + 4);
      gws[0][k] = g0.x; gws[1][k] = g0.y; gws[2][k] = g0.z; gws[3][k] = g0.w;
      gws[4][k] = g1.x; gws[5][k] = g1.y; gws[6][k] = g1.z; gws[7][k] = g1.w;
    }
    if (t < 64) hh[t] = 0;
    __syncthreads();

    const int wave = t >> 6, l = t & 63;
    const int r0 = bid * 8 + wave * 2;

    float4 xv0[4], xv1[4];
#pragma unroll
    for (int j = 0; j < 4; ++j) {
      xv0[j] = *(const float4*)(x + (size_t)r0 * IN_DIM + j * 256 + l * 4);
      xv1[j] = *(const float4*)(x + (size_t)(r0 + 1) * IN_DIM + j * 256 + l * 4);
    }

    if (xb) {
#pragma unroll
      for (int j = 0; j < 4; ++j) {
        uint2 p0, p1;
        p0.x = (unsigned)f2bf(xv0[j].x) | ((unsigned)f2bf(xv0[j].y) << 16);
        p0.y = (unsigned)f2bf(xv0[j].z) | ((unsigned)f2bf(xv0[j].w) << 16);
        p1.x = (unsigned)f2bf(xv1[j].x) | ((unsigned)f2bf(xv1[j].y) << 16);
        p1.y = (unsigned)f2bf(xv1[j].z) | ((unsigned)f2bf(xv1[j].w) << 16);
        *(uint2*)(xb + (size_t)r0 * IN_DIM + j * 256 + l * 4)       = p0;
        *(uint2*)(xb + (size_t)(r0 + 1) * IN_DIM + j * 256 + l * 4) = p1;
      }
    }

    float a0[NEXP], a1[NEXP];
#pragma unroll
    for (int e = 0; e < NEXP; ++e) { a0[e] = 0.f; a1[e] = 0.f; }
#pragma unroll
    for (int e = 0; e < NEXP; ++e) {
#pragma unroll
      for (int j = 0; j < 4; ++j) {
        const float4 g = *(const float4*)&gws[e][j * 256 + l * 4];
        a0[e] = fmaf(xv0[j].x, g.x, a0[e]); a0[e] = fmaf(xv0[j].y, g.y, a0[e]);
        a0[e] = fmaf(xv0[j].z, g.z, a0[e]); a0[e] = fmaf(xv0[j].w, g.w, a0[e]);
        a1[e] = fmaf(xv1[j].x, g.x, a1[e]); a1[e] = fmaf(xv1[j].y, g.y, a1[e]);
        a1[e] = fmaf(xv1[j].z, g.z, a1[e]); a1[e] = fmaf(xv1[j].w, g.w, a1[e]);
      }
    }
#pragma unroll
    for (int e = 0; e < NEXP; ++e) {
#pragma unroll
      for (int off = 32; off > 0; off >>= 1) {
        a0[e] += __shfl_xor(a0[e], off);
        a1[e] += __shfl_xor(a1[e], off);
      }
    }

    if (l == 0) {
      float sv0 = 0.f, sv1 = 0.f;
#pragma unroll
      for (int rr = 0; rr < 2; ++rr) {
        const float* a = rr ? a1 : a0;
        float lg[NEXP];
#pragma unroll
        for (int e = 0; e < NEXP; ++e) lg[e] = a[e] + gb[e];
        float m = lg[0];
#pragma unroll
        for (int e = 1; e < NEXP; ++e) m = fmaxf(m, lg[e]);
        float p[NEXP], s = 0.f;
#pragma unroll
        for (int e = 0; e < NEXP; ++e) { p[e] = __expf(lg[e] - m); s += p[e]; }
        const float inv = 1.f / s;
        int   i0 = 0;  float v0 = p[0];
#pragma unroll
        for (int e = 1; e < NEXP; ++e) if (p[e] > v0) { v0 = p[e]; i0 = e; }
        int   i1 = -1; float v1 = -1.f;
#pragma unroll
        for (int e = 0; e < NEXP; ++e)
          if (e != i0 && p[e] > v1) { v1 = p[e]; i1 = e; }
        tval[r0 + rr] = make_float2(v0 * inv, v1 * inv);
        const int pr = i0 * 7 + i1 - (i1 > i0 ? 1 : 0);
        pairid[r0 + rr] = (unsigned char)pr;
        sv0 += v0 * inv; sv1 += v1 * inv;
        atomicAdd(&hh[pr], 1);
        atomicAdd(&hh[56 + i0], 1);
        atomicAdd(&hh[56 + i1], 1);
      }
      ps[wave * 2]     = sv0;
      ps[wave * 2 + 1] = sv1;
    }
    __syncthreads();
    if (t < 64) partials[(size_t)bid * 64 + t] = hh[t];
    if (t == 0)
      psum[bid] = make_float2(ps[0] + ps[2] + ps[4] + ps[6],
                              ps[1] + ps[3] + ps[5] + ps[7]);
  } else {
    float (*tile)[33] = (float(*)[33])pmem;
    const float* src; unsigned short* dst;
    int R, C, r0, c0, e;
    if (bid < GATE_BLOCKS + W1T_BLOCKS) {
      const int b1 = bid - GATE_BLOCKS;
      e = b1 >> 7; const int rem = b1 & 127;
      R = IN_DIM; C = HID;
      c0 = (rem & 3) * 32; r0 = (rem >> 2) * 32;
      src = w1; dst = w1bt;
    } else {
      const int b2 = bid - GATE_BLOCKS - W1T_BLOCKS;
      e = b2 >> 7; const int rem = b2 & 127;
      R = HID; C = NCLS;
      c0 = (rem & 31) * 32; r0 = (rem >> 5) * 32;
      src = w2; dst = w2bt;
    }
    src += (size_t)e * R * C;
    dst += (size_t)e * R * C;
    const int tx = t & 31, ty = t >> 5;
#pragma unroll
    for (int i = ty; i < 32; i += 8)
      tile[i][tx] = src[(size_t)(r0 + i) * C + c0 + tx];
    __syncthreads();
#pragma unroll
    for (int i = ty; i < 32; i += 8)
      dst[(size_t)(c0 + i) * R + r0 + tx] = f2bf(tile[tx][i]);
  }
}

// ---------------------------------------------------------------------------
// Scan (256 threads): COALESCED int4 sweep over partials (thread t reads
// flat int4 index t+256i; its 4 lanes always map to bins (4t)&63 ..+3) ->
// 4 LDS atomics/thread -> hist. psum tree-reduce -> gates output. Thread 0
// builds exclusive bases, cursors, exact work lists.
// ---------------------------------------------------------------------------
__global__ __launch_bounds__(256) void scan_kernel(
    const int* __restrict__ partials, const float2* __restrict__ psum,
    int* __restrict__ hist, int* __restrict__ base, int* __restrict__ csr,
    int* __restrict__ meta, float* __restrict__ out) {
  const int t = threadIdx.x;
  __shared__ int hsum[64];
  __shared__ float r0a[256], r1a[256];
  __shared__ float gg[2];

  if (t < 64) hsum[t] = 0;
  __syncthreads();

  // coalesced sweep: 2048*64 ints = 32768 int4; 256 thr * 128 iters
  {
    const int4* p4 = (const int4*)partials;
    int sx = 0, sy = 0, sz = 0, sw = 0;
#pragma unroll 8
    for (int i = 0; i < (GATE_BLOCKS * 64 / 4) / 256; ++i) {
      const int4 v = p4[t + 256 * i];
      sx += v.x; sy += v.y; sz += v.z; sw += v.w;
    }
    const int b0 = (4 * t) & 63;
    atomicAdd(&hsum[b0 + 0], sx);
    atomicAdd(&hsum[b0 + 1], sy);
    atomicAdd(&hsum[b0 + 2], sz);
    atomicAdd(&hsum[b0 + 3], sw);
  }
  // psum partial sums (8 iters, coalesced)
  {
    float g0 = 0.f, g1 = 0.f;
    for (int b = t; b < GATE_BLOCKS; b += 256) { g0 += psum[b].x; g1 += psum[b].y; }
    r0a[t] = g0; r1a[t] = g1;
  }
  __syncthreads();
  if (t < 64) hist[t] = hsum[t];
#pragma unroll
  for (int s = 128; s > 0; s >>= 1) {
    if (t < s) { r0a[t] += r0a[t + s]; r1a[t] += r1a[t + s]; }
    __syncthreads();
  }
  if (t == 0) { gg[0] = r0a[0]; gg[1] = r1a[0]; }
  __syncthreads();

  float* gout = out + (size_t)B_ROWS * NCLS;
  for (int c = t; c < NCLS; c += 256) {
    gout[c]        = gg[0];
    gout[NCLS + c] = gg[1];
  }
  if (t != 0) return;
  int accp = 0, acce = 0;
  for (int p = 0; p < NPAIR; ++p) { base[p] = accp; csr[p] = accp; accp += hist[p]; }
  for (int e = 0; e < NEXP; ++e) {
    base[56 + e] = acce; csr[56 + e] = acce; acce += hist[56 + e];
  }
  int n = 0;
  int* w1 = meta + 2;
  for (int e = 0; e < NEXP; ++e) {
    const int tiles = (hist[56 + e] + 63) >> 6;
    for (int i = 0; i < tiles; ++i) w1[n++] = (e << 16) | i;
  }
  meta[0] = n;
  n = 0;
  int* w2 = meta + 2 + MAXW1;
  for (int p = 0; p < NPAIR; ++p) {
    const int tiles = (hist[p] + 63) >> 6;
    for (int i = 0; i < tiles; ++i) w2[n++] = (p << 16) | i;
  }
  meta[1] = n;
}

// ---------------------------------------------------------------------------
// Scatter: per-block LDS histogram -> one aggregated atomic per bin per block.
// elist entry = (pp << 15) | (row << 1) | slot  (pp = plist position).
// ---------------------------------------------------------------------------
__global__ __launch_bounds__(256) void scatter_kernel(
    const unsigned char* __restrict__ pairid, int* __restrict__ csr,
    int* __restrict__ elist, int* __restrict__ plist) {
  __shared__ int h[64], lbase[64];
  const int t = threadIdx.x;
  if (t < 64) h[t] = 0;
  __syncthreads();
  const int row = blockIdx.x * 256 + t;
  const int p  = pairid[row];
  const int ea = p / 7, rem = p % 7;
  const int eb = rem + (rem >= ea ? 1 : 0);
  const int op = atomicAdd(&h[p], 1);
  const int oa = atomicAdd(&h[56 + ea], 1);
  const int ob = atomicAdd(&h[56 + eb], 1);
  __syncthreads();
  if (t < 64) lbase[t] = h[t] ? atomicAdd(&csr[t], h[t]) : 0;
  __syncthreads();
  const int pp = lbase[p] + op;                   // plist position
  plist[pp] = row;
  elist[lbase[56 + ea] + oa] = (pp << 15) | (row << 1);
  elist[lbase[56 + eb] + ob] = (pp << 15) | (row << 1) | 1;
}

// ---------------------------------------------------------------------------
// K1: hidden GEMM, expert-grouped. Writes Hg in PLIST ORDER (index pp from
// the packed elist entry) so k2's A-tile read is sequential.
// ---------------------------------------------------------------------------
template <bool XB>
__global__ __launch_bounds__(256) void k1_hidden(
    const float* __restrict__ x, const unsigned short* __restrict__ xb,
    const unsigned short* __restrict__ w1bt, const float* __restrict__ b1,
    const float2* __restrict__ tval, const int* __restrict__ elist,
    const int* __restrict__ hist, const int* __restrict__ base,
    const int* __restrict__ meta, unsigned short* __restrict__ Hg) {
  const int b = blockIdx.x;
  if (b >= meta[0]) return;
  const int item = meta[2 + b];
  const int e = item >> 16, tile = item & 0xffff;
  const int start = tile * 64;
  const int nr = min(64, hist[56 + e] - start);

  __shared__ unsigned short As[64 * 64];
  __shared__ unsigned short Bs[128 * 64];
  __shared__ int rowl[64];

  const int t = threadIdx.x;
  if (t < 64) rowl[t] = elist[base[56 + e] + start + (t < nr ? t : 0)];
  __syncthreads();

  const int wid = t >> 6, l = t & 63;
  const int wr = wid >> 1, wc = wid & 1;
  const int lg = l >> 4,   ln = l & 15;

  f32x4 acc[2][4];
#pragma unroll
  for (int ms = 0; ms < 2; ++ms)
#pragma unroll
    for (int nf = 0; nf < 4; ++nf) acc[ms][nf] = (f32x4){0.f, 0.f, 0.f, 0.f};

  const int ai = t >> 2, aseg = t & 3;
  const int arow = (rowl[ai] >> 1) & 0x3FFF;
  const float* asrcf = x + (size_t)arow * IN_DIM + aseg * 16;
  const unsigned short* asrcb = xb + (size_t)arow * IN_DIM + aseg * 16;
  const int bn = t >> 1, bhf = t & 1;
  const unsigned short* bsrc =
      w1bt + ((size_t)e * HID + bn) * IN_DIM + bhf * 32;

  if constexpr (XB) {
    u32x4 areg[2], breg[4];
    {
      const u32x4* ap = (const u32x4*)(asrcb);
      areg[0] = ap[0]; areg[1] = ap[1];
      const u32x4* bp = (const u32x4*)(bsrc);
#pragma unroll
      for (int j = 0; j < 4; ++j) breg[j] = bp[j];
    }
    for (int ks = 0; ks < 16; ++ks) {
      *(u32x4*)&As[sw64(ai, aseg * 16)]     = areg[0];
      *(u32x4*)&As[sw64(ai, aseg * 16 + 8)] = areg[1];
#pragma unroll
      for (int j = 0; j < 4; ++j)
        *(u32x4*)&Bs[sw64(bn, bhf * 32 + j * 8)] = breg[j];
      __syncthreads();
      if (ks < 15) {
        const u32x4* ap = (const u32x4*)(asrcb + (ks + 1) * 64);
        areg[0] = ap[0]; areg[1] = ap[1];
        const u32x4* bp = (const u32x4*)(bsrc + (ks + 1) * 64);
#pragma unroll
        for (int j = 0; j < 4; ++j) breg[j] = bp[j];
      }
      bf16x8 af[2][2], bf[4][2];
#pragma unroll
      for (int ms = 0; ms < 2; ++ms)
#pragma unroll
        for (int kh = 0; kh < 2; ++kh)
          af[ms][kh] = *(const bf16x8*)&As[sw64(wr*32 + ms*16 + ln, kh*32 + lg*8)];
#pragma unroll
      for (int nf = 0; nf < 4; ++nf)
#pragma unroll
        for (int kh = 0; kh < 2; ++kh)
          bf[nf][kh] = *(const bf16x8*)&Bs[sw64(wc*64 + nf*16 + ln, kh*32 + lg*8)];
#pragma unroll
      for (int ms = 0; ms < 2; ++ms)
#pragma unroll
        for (int nf = 0; nf < 4; ++nf) {
          acc[ms][nf] = __builtin_amdgcn_mfma_f32_16x16x32_bf16(af[ms][0], bf[nf][0], acc[ms][nf], 0, 0, 0);
          acc[ms][nf] = __builtin_amdgcn_mfma_f32_16x16x32_bf16(af[ms][1], bf[nf][1], acc[ms][nf], 0, 0, 0);
        }
      __syncthreads();
    }
  } else {
    for (int ks = 0; ks < 16; ++ks) {
      {
        const float4 f0 = *(const float4*)(asrcf + ks * 64);
        const float4 f1 = *(const float4*)(asrcf + ks * 64 + 4);
        const float4 f2 = *(const float4*)(asrcf + ks * 64 + 8);
        const float4 f3 = *(const float4*)(asrcf + ks * 64 + 12);
        u16x8 u0, u1;
        u0[0]=f2bf(f0.x); u0[1]=f2bf(f0.y); u0[2]=f2bf(f0.z); u0[3]=f2bf(f0.w);
        u0[4]=f2bf(f1.x); u0[5]=f2bf(f1.y); u0[6]=f2bf(f1.z); u0[7]=f2bf(f1.w);
        u1[0]=f2bf(f2.x); u1[1]=f2bf(f2.y); u1[2]=f2bf(f2.z); u1[3]=f2bf(f2.w);
        u1[4]=f2bf(f3.x); u1[5]=f2bf(f3.y); u1[6]=f2bf(f3.z); u1[7]=f2bf(f3.w);
        *(u16x8*)&As[sw64(ai, aseg * 16)]     = u0;
        *(u16x8*)&As[sw64(ai, aseg * 16 + 8)] = u1;
      }
      {
        const u32x4* bp = (const u32x4*)(bsrc + ks * 64);
#pragma unroll
        for (int j = 0; j < 4; ++j)
          *(u32x4*)&Bs[sw64(bn, bhf * 32 + j * 8)] = bp[j];
      }
      __syncthreads();
      bf16x8 af[2][2], bf[4][2];
#pragma unroll
      for (int ms = 0; ms < 2; ++ms)
#pragma unroll
        for (int kh = 0; kh < 2; ++kh)
          af[ms][kh] = *(const bf16x8*)&As[sw64(wr*32 + ms*16 + ln, kh*32 + lg*8)];
#pragma unroll
      for (int nf = 0; nf < 4; ++nf)
#pragma unroll
        for (int kh = 0; kh < 2; ++kh)
          bf[nf][kh] = *(const bf16x8*)&Bs[sw64(wc*64 + nf*16 + ln, kh*32 + lg*8)];
#pragma unroll
      for (int ms = 0; ms < 2; ++ms)
#pragma unroll
        for (int nf = 0; nf < 4; ++nf) {
          acc[ms][nf] = __builtin_amdgcn_mfma_f32_16x16x32_bf16(af[ms][0], bf[nf][0], acc[ms][nf], 0, 0, 0);
          acc[ms][nf] = __builtin_amdgcn_mfma_f32_16x16x32_bf16(af[ms][1], bf[nf][1], acc[ms][nf], 0, 0, 0);
        }
      __syncthreads();
    }
  }

  float b1c[4];
#pragma unroll
  for (int nf = 0; nf < 4; ++nf) b1c[nf] = b1[e * HID + wc*64 + nf*16 + ln];

#pragma unroll
  for (int ms = 0; ms < 2; ++ms)
#pragma unroll
    for (int r = 0; r < 4; ++r) {
      const int li = wr*32 + ms*16 + lg*4 + r;
      if (li < nr) {
        const int packed = rowl[li];
        const int row  = (packed >> 1) & 0x3FFF;
        const int slot = packed & 1;
        const int pp   = ((unsigned)packed) >> 15;
        const float2 tv = tval[row];
        const float vv = slot ? tv.y : tv.x;
#pragma unroll
        for (int nf = 0; nf < 4; ++nf) {
          const float hh = fmaxf(acc[ms][nf][r] + b1c[nf], 0.f) * vv;
          Hg[((size_t)pp * 2 + slot) * HID + wc*64 + nf*16 + ln] = f2bf(hh);
        }
      }
    }
}

// ---------------------------------------------------------------------------
// K2: output GEMM, pair-grouped. Two c-halves per block: the sequential
// 32 KB Ah stage is amortized over 256 output columns (Hg re-staging 8x->4x)
// while keeping the round-8 register budget (acc[2][4] per half).
// ---------------------------------------------------------------------------
__global__ __launch_bounds__(256) void k2_out(
    const unsigned short* __restrict__ Hg, const unsigned short* __restrict__ w2bt,
    const float* __restrict__ b2, const float2* __restrict__ tval,
    const int* __restrict__ plist, const int* __restrict__ hist,
    const int* __restrict__ base, const int* __restrict__ meta,
    float* __restrict__ out) {
  const int b = blockIdx.y;
  if (b >= meta[1]) return;
  const int item = meta[2 + MAXW1 + b];
  const int p = item >> 16, rt = item & 0xffff;
  const int ea = p / 7, rem = p % 7;
  const int eb = rem + (rem >= ea ? 1 : 0);
  const int start = rt * 64;
  const int gpos = base[p] + start;          // plist-global row-tile start
  const int nr = min(64, hist[p] - start);
  const int c0base = blockIdx.x * 256;

  __shared__ unsigned short Ah[64 * 256];   // 32 KB, staged once (sequential)
  __shared__ unsigned short Bs[128 * 64];   // 16 KB, per-ks
  __shared__ int rowl[64];
  __shared__ float2 vals[64];

  const int t = threadIdx.x;
  if (t < 64) {
    const int r = plist[gpos + (t < nr ? t : 0)];
    rowl[t] = r;
    vals[t] = tval[r];
  }
  __syncthreads();

  // stage A: rows gpos..gpos+63 of plist-ordered Hg -> contiguous 32 KB
  {
    const int i = t >> 2, q = t & 3;
    const int srow = min(gpos + i, B_ROWS - 1);   // clamp tail padding
    const u32x4* src = (const u32x4*)(Hg + (size_t)srow * 256 + q * 64);
#pragma unroll
    for (int j = 0; j < 8; ++j)
      *(u32x4*)&Ah[sw256(i, q * 64 + j * 8)] = src[j];
  }

  const int wid = t >> 6, l = t & 63;
  const int wr = wid >> 1, wc = wid & 1;
  const int lg = l >> 4,   ln = l & 15;
  const int bn = t >> 1, bhf = t & 1;

#pragma unroll
  for (int ch2 = 0; ch2 < 2; ++ch2) {
    const int c0 = c0base + ch2 * 128;

    f32x4 acc[2][4];
#pragma unroll
    for (int ms = 0; ms < 2; ++ms)
#pragma unroll
      for (int nf = 0; nf < 4; ++nf) acc[ms][nf] = (f32x4){0.f, 0.f, 0.f, 0.f};

    u32x4 breg[4];
    {
      const u32x4* bp = (const u32x4*)(
          w2bt + ((size_t)ea * NCLS + c0 + bn) * HID + bhf * 32);
#pragma unroll
      for (int j = 0; j < 4; ++j) breg[j] = bp[j];
    }
#pragma unroll
    for (int ks = 0; ks < 4; ++ks) {
#pragma unroll
      for (int j = 0; j < 4; ++j)
        *(u32x4*)&Bs[sw64(bn, bhf * 32 + j * 8)] = breg[j];
      __syncthreads();
      if (ks < 3) {   // prefetch next ks; hides under ds_read+MFMA
        const int exn = (ks + 1 < 2) ? ea : eb;
        const int hbn = ((ks + 1) & 1) * 64;
        const u32x4* bp = (const u32x4*)(
            w2bt + ((size_t)exn * NCLS + c0 + bn) * HID + hbn + bhf * 32);
#pragma unroll
        for (int j = 0; j < 4; ++j) breg[j] = bp[j];
      }
      bf16x8 af[2][2], bf[4][2];
#pragma unroll
      for (int ms = 0; ms < 2; ++ms)
#pragma unroll
        for (int kh = 0; kh < 2; ++kh)
          af[ms][kh] = *(const bf16x8*)&Ah[sw256(wr*32 + ms*16 + ln, ks*64 + kh*32 + lg*8)];
#pragma unroll
      for (int nf = 0; nf < 4; ++nf)
#pragma unroll
        for (int kh = 0; kh < 2; ++kh)
          bf[nf][kh] = *(const bf16x8*)&Bs[sw64(wc*64 + nf*16 + ln, kh*32 + lg*8)];
#pragma unroll
      for (int ms = 0; ms < 2; ++ms)
#pragma unroll
        for (int nf = 0; nf < 4; ++nf) {
          acc[ms][nf] = __builtin_amdgcn_mfma_f32_16x16x32_bf16(af[ms][0], bf[nf][0], acc[ms][nf], 0, 0, 0);
          acc[ms][nf] = __builtin_amdgcn_mfma_f32_16x16x32_bf16(af[ms][1], bf[nf][1], acc[ms][nf], 0, 0, 0);
        }
      __syncthreads();
    }

    float b2a[4], b2b[4];
#pragma unroll
    for (int nf = 0; nf < 4; ++nf) {
      const int c = c0 + wc*64 + nf*16 + ln;
      b2a[nf] = b2[ea * NCLS + c];
      b2b[nf] = b2[eb * NCLS + c];
    }
#pragma unroll
    for (int ms = 0; ms < 2; ++ms)
#pragma unroll
      for (int r = 0; r < 4; ++r) {
        const int li = wr*32 + ms*16 + lg*4 + r;
        if (li < nr) {
          const int row = rowl[li];
          const float2 v = vals[li];
#pragma unroll
          for (int nf = 0; nf < 4; ++nf) {
            const int c = c0 + wc*64 + nf*16 + ln;
            out[(size_t)row * NCLS + c] = acc[ms][nf][r] + v.x * b2a[nf] + v.y * b2b[nf];
          }
        }
      }
  }
}

extern "C" void kernel_launch(void* const* d_in, const int* in_sizes, int n_in,
                              void* d_out, int out_size, void* d_ws, size_t ws_size,
                              hipStream_t stream) {
  const float* x   = (const float*)d_in[0];
  const float* gw  = (const float*)d_in[1];
  const float* gb  = (const float*)d_in[2];
  const float* w1  = (const float*)d_in[3];
  const float* b1  = (const float*)d_in[4];
  const float* w2  = (const float*)d_in[5];
  const float* b2  = (const float*)d_in[6];
  float* out = (float*)d_out;

  // ws layout (bytes). Nothing needs pre-zeroing:
  //   hist 0..256 | base 256..512 | csr 512..768 | meta 768..4104 (pad 4352)
  //   partials 4352..528640 (2048*64 int) | psum 528640..545024
  //   pairid 545024..561408 | tval 561408..692480
  //   elist 692480..823552 | plist 823552..889088
  //   w1bt 889088..2986240 | w2bt 2986240..5083392 | Hg 5083392..13472000
  //   xb  13472000..47026432 (optional)
  char* ws = (char*)d_ws;
  int*            hist     = (int*)(ws);
  int*            base     = (int*)(ws + 256);
  int*            csr      = (int*)(ws + 512);
  int*            meta     = (int*)(ws + 768);
  int*            partials = (int*)(ws + 4352);
  float2*         psum     = (float2*)(ws + 528640);
  unsigned char*  pairid   = (unsigned char*)(ws + 545024);
  float2*         tval     = (float2*)(ws + 561408);
  int*            elist    = (int*)(ws + 692480);
  int*            plist    = (int*)(ws + 823552);
  unsigned short* w1bt     = (unsigned short*)(ws + 889088);
  unsigned short* w2bt     = (unsigned short*)(ws + 2986240);
  unsigned short* Hg       = (unsigned short*)(ws + 5083392);
  const bool use_xb = (ws_size >= (size_t)47026432);
  unsigned short* xb = use_xb ? (unsigned short*)(ws + 13472000) : nullptr;

  prep_kernel<<<GATE_BLOCKS + W1T_BLOCKS + W2T_BLOCKS, 256, 0, stream>>>(
      x, gw, gb, w1, w2, xb, w1bt, w2bt, tval, pairid, partials, psum);
  scan_kernel<<<1, 256, 0, stream>>>(partials, psum, hist, base, csr, meta, out);
  scatter_kernel<<<B_ROWS / 256, 256, 0, stream>>>(pairid, csr, elist, plist);

  if (use_xb)
    k1_hidden<true><<<MAXW1, 256, 0, stream>>>(x, xb, w1bt, b1, tval, elist,
                                               hist, base, meta, Hg);
  else
    k1_hidden<false><<<MAXW1, 256, 0, stream>>>(x, xb, w1bt, b1, tval, elist,
                                                hist, base, meta, Hg);
  k2_out<<<dim3(NCLS / 256, MAXW2), 256, 0, stream>>>(Hg, w2bt, b2, tval, plist,
                                                      hist, base, meta, out);
}

// Round 16
// 116.451 us; speedup vs baseline: 1.6089x; 1.0890x over previous
//
#include <hip/hip_runtime.h>

#define B_ROWS  16384
#define IN_DIM  1024
#define NEXP    8
#define HID     128
#define NCLS    1024
#define NPAIR   56
#define MAXW1   520   // max K1 work items: 32768/64 + 8
#define MAXW2   312   // max K2 work items: 16384/64 + 56

#define GATE_BLOCKS (B_ROWS / 8)                        // 2048
#define W1T_BLOCKS  (NEXP * (IN_DIM / 32) * (HID / 32)) // 1024
#define W2T_BLOCKS  (NEXP * (HID / 32) * (NCLS / 32))   // 1024

typedef __attribute__((ext_vector_type(8))) short bf16x8;
typedef __attribute__((ext_vector_type(4))) float f32x4;
typedef __attribute__((ext_vector_type(4))) unsigned int u32x4;
typedef __attribute__((ext_vector_type(8))) unsigned short u16x8;

__device__ __forceinline__ unsigned short f2bf(float f) {
  union { float f; unsigned u; } v; v.f = f;
  unsigned r = v.u + 0x7FFFu + ((v.u >> 16) & 1u);
  return (unsigned short)(r >> 16);
}

// XOR-swizzled LDS addressing (T2): linear rows, 8-short (16B) slots,
// slot ^= row&7.
__device__ __forceinline__ int sw64(int row, int sh) {   // 64-short rows
  return (row << 6) + ((((sh >> 3) ^ row) & 7) << 3) + (sh & 7);
}
__device__ __forceinline__ int sw256(int row, int sh) {  // 256-short rows
  return (row << 8) + ((((sh >> 3) ^ row) & 7) << 3) + (sh & 7) + ((sh >> 6) << 6);
}

// ---------------------------------------------------------------------------
// Fused prep: blocks [0,2048) gate+x->bf16; [2048,3072) w1 transpose;
// [3072,4096) w2 transpose.
// ---------------------------------------------------------------------------
__global__ __launch_bounds__(256) void prep_kernel(
    const float* __restrict__ x, const float* __restrict__ gw,
    const float* __restrict__ gb, const float* __restrict__ w1,
    const float* __restrict__ w2, unsigned short* __restrict__ xb,
    unsigned short* __restrict__ w1bt, unsigned short* __restrict__ w2bt,
    float2* __restrict__ tval, unsigned char* __restrict__ pairid) {
  __shared__ __attribute__((aligned(16))) unsigned char pmem[NEXP * IN_DIM * 4];
  const int bid = blockIdx.x;
  const int t = threadIdx.x;

  if (bid < GATE_BLOCKS) {
    float (*gws)[IN_DIM] = (float(*)[IN_DIM])pmem;   // 32 KB
#pragma unroll
    for (int kk = 0; kk < 4; ++kk) {
      const int k = kk * 256 + t;
      const float4 g0 = *(const float4*)(gw + k * NEXP);
      const float4 g1 = *(const float4*)(gw + k * NEXP + 4);
      gws[0][k] = g0.x; gws[1][k] = g0.y; gws[2][k] = g0.z; gws[3][k] = g0.w;
      gws[4][k] = g1.x; gws[5][k] = g1.y; gws[6][k] = g1.z; gws[7][k] = g1.w;
    }
    __syncthreads();

    const int wave = t >> 6, l = t & 63;
    const int r0 = bid * 8 + wave * 2;

    float4 xv0[4], xv1[4];
#pragma unroll
    for (int j = 0; j < 4; ++j) {
      xv0[j] = *(const float4*)(x + (size_t)r0 * IN_DIM + j * 256 + l * 4);
      xv1[j] = *(const float4*)(x + (size_t)(r0 + 1) * IN_DIM + j * 256 + l * 4);
    }

    if (xb) {
#pragma unroll
      for (int j = 0; j < 4; ++j) {
        uint2 p0, p1;
        p0.x = (unsigned)f2bf(xv0[j].x) | ((unsigned)f2bf(xv0[j].y) << 16);
        p0.y = (unsigned)f2bf(xv0[j].z) | ((unsigned)f2bf(xv0[j].w) << 16);
        p1.x = (unsigned)f2bf(xv1[j].x) | ((unsigned)f2bf(xv1[j].y) << 16);
        p1.y = (unsigned)f2bf(xv1[j].z) | ((unsigned)f2bf(xv1[j].w) << 16);
        *(uint2*)(xb + (size_t)r0 * IN_DIM + j * 256 + l * 4)       = p0;
        *(uint2*)(xb + (size_t)(r0 + 1) * IN_DIM + j * 256 + l * 4) = p1;
      }
    }

    float a0[NEXP], a1[NEXP];
#pragma unroll
    for (int e = 0; e < NEXP; ++e) { a0[e] = 0.f; a1[e] = 0.f; }
#pragma unroll
    for (int e = 0; e < NEXP; ++e) {
#pragma unroll
      for (int j = 0; j < 4; ++j) {
        const float4 g = *(const float4*)&gws[e][j * 256 + l * 4];
        a0[e] = fmaf(xv0[j].x, g.x, a0[e]); a0[e] = fmaf(xv0[j].y, g.y, a0[e]);
        a0[e] = fmaf(xv0[j].z, g.z, a0[e]); a0[e] = fmaf(xv0[j].w, g.w, a0[e]);
        a1[e] = fmaf(xv1[j].x, g.x, a1[e]); a1[e] = fmaf(xv1[j].y, g.y, a1[e]);
        a1[e] = fmaf(xv1[j].z, g.z, a1[e]); a1[e] = fmaf(xv1[j].w, g.w, a1[e]);
      }
    }
#pragma unroll
    for (int e = 0; e < NEXP; ++e) {
#pragma unroll
      for (int off = 32; off > 0; off >>= 1) {
        a0[e] += __shfl_xor(a0[e], off);
        a1[e] += __shfl_xor(a1[e], off);
      }
    }

    if (l == 0) {
#pragma unroll
      for (int rr = 0; rr < 2; ++rr) {
        const float* a = rr ? a1 : a0;
        float lg[NEXP];
#pragma unroll
        for (int e = 0; e < NEXP; ++e) lg[e] = a[e] + gb[e];
        float m = lg[0];
#pragma unroll
        for (int e = 1; e < NEXP; ++e) m = fmaxf(m, lg[e]);
        float p[NEXP], s = 0.f;
#pragma unroll
        for (int e = 0; e < NEXP; ++e) { p[e] = __expf(lg[e] - m); s += p[e]; }
        const float inv = 1.f / s;
        int   i0 = 0;  float v0 = p[0];
#pragma unroll
        for (int e = 1; e < NEXP; ++e) if (p[e] > v0) { v0 = p[e]; i0 = e; }
        int   i1 = -1; float v1 = -1.f;
#pragma unroll
        for (int e = 0; e < NEXP; ++e)
          if (e != i0 && p[e] > v1) { v1 = p[e]; i1 = e; }
        tval[r0 + rr] = make_float2(v0 * inv, v1 * inv);
        pairid[r0 + rr] = (unsigned char)(i0 * 7 + i1 - (i1 > i0 ? 1 : 0));
      }
    }
  } else {
    float (*tile)[33] = (float(*)[33])pmem;
    const float* src; unsigned short* dst;
    int R, C, r0, c0, e;
    if (bid < GATE_BLOCKS + W1T_BLOCKS) {
      const int b1 = bid - GATE_BLOCKS;
      e = b1 >> 7; const int rem = b1 & 127;
      R = IN_DIM; C = HID;
      c0 = (rem & 3) * 32; r0 = (rem >> 2) * 32;
      src = w1; dst = w1bt;
    } else {
      const int b2 = bid - GATE_BLOCKS - W1T_BLOCKS;
      e = b2 >> 7; const int rem = b2 & 127;
      R = HID; C = NCLS;
      c0 = (rem & 31) * 32; r0 = (rem >> 5) * 32;
      src = w2; dst = w2bt;
    }
    src += (size_t)e * R * C;
    dst += (size_t)e * R * C;
    const int tx = t & 31, ty = t >> 5;
#pragma unroll
    for (int i = ty; i < 32; i += 8)
      tile[i][tx] = src[(size_t)(r0 + i) * C + c0 + tx];
    __syncthreads();
#pragma unroll
    for (int i = ty; i < 32; i += 8)
      dst[(size_t)(c0 + i) * R + r0 + tx] = f2bf(tile[tx][i]);
  }
}

// ---------------------------------------------------------------------------
// Per-block partial histograms + partial tval sums (init-free).
// ---------------------------------------------------------------------------
__global__ __launch_bounds__(256) void hist_part_kernel(
    const unsigned char* __restrict__ pairid, const float2* __restrict__ tval,
    int* __restrict__ partials, float2* __restrict__ psum) {
  __shared__ int h[64];
  __shared__ float s0a[256], s1a[256];
  const int t = threadIdx.x;
  if (t < 64) h[t] = 0;
  __syncthreads();
  const int row = blockIdx.x * 256 + t;
  const int p  = pairid[row];
  const int ea = p / 7, rem = p % 7;
  const int eb = rem + (rem >= ea ? 1 : 0);
  atomicAdd(&h[p], 1);
  atomicAdd(&h[56 + ea], 1);
  atomicAdd(&h[56 + eb], 1);
  const float2 v = tval[row];
  s0a[t] = v.x; s1a[t] = v.y;
  __syncthreads();
#pragma unroll
  for (int s = 128; s > 0; s >>= 1) {
    if (t < s) { s0a[t] += s0a[t + s]; s1a[t] += s1a[t + s]; }
    __syncthreads();
  }
  if (t < 64) partials[blockIdx.x * 64 + t] = h[t];
  if (t == 0) psum[blockIdx.x] = make_float2(s0a[0], s1a[0]);
}

// ---------------------------------------------------------------------------
// Scan: sum partials -> hist; exclusive bases, cursors, exact work lists;
// also reduces psum and writes the gates_sum output rows.
// ---------------------------------------------------------------------------
__global__ void scan_kernel(const int* __restrict__ partials,
                            const float2* __restrict__ psum,
                            int* __restrict__ hist, int* __restrict__ base,
                            int* __restrict__ csr, int* __restrict__ meta,
                            float* __restrict__ out) {
  const int t = threadIdx.x;
  __shared__ float gg[2];
  if (t < 64) {
    int s = 0;
    for (int b = 0; b < B_ROWS / 256; ++b) s += partials[b * 64 + t];
    hist[t] = s;
  }
  if (t == 0) {
    float g0 = 0.f, g1 = 0.f;
    for (int b = 0; b < B_ROWS / 256; ++b) { g0 += psum[b].x; g1 += psum[b].y; }
    gg[0] = g0; gg[1] = g1;
  }
  __syncthreads();
  float* gout = out + (size_t)B_ROWS * NCLS;
  for (int c = t; c < NCLS; c += 64) {
    gout[c]        = gg[0];
    gout[NCLS + c] = gg[1];
  }
  if (t != 0) return;
  int accp = 0, acce = 0;
  for (int p = 0; p < NPAIR; ++p) { base[p] = accp; csr[p] = accp; accp += hist[p]; }
  for (int e = 0; e < NEXP; ++e) {
    base[56 + e] = acce; csr[56 + e] = acce; acce += hist[56 + e];
  }
  int n = 0;
  int* w1 = meta + 2;
  for (int e = 0; e < NEXP; ++e) {
    const int tiles = (hist[56 + e] + 63) >> 6;
    for (int i = 0; i < tiles; ++i) w1[n++] = (e << 16) | i;
  }
  meta[0] = n;
  n = 0;
  int* w2 = meta + 2 + MAXW1;
  for (int p = 0; p < NPAIR; ++p) {
    const int tiles = (hist[p] + 63) >> 6;
    for (int i = 0; i < tiles; ++i) w2[n++] = (p << 16) | i;
  }
  meta[1] = n;
}

// ---------------------------------------------------------------------------
// Scatter: per-block LDS histogram -> one aggregated atomic per bin per block.
// elist entry = (pp << 15) | (row << 1) | slot  (pp = plist position).
// ---------------------------------------------------------------------------
__global__ __launch_bounds__(256) void scatter_kernel(
    const unsigned char* __restrict__ pairid, int* __restrict__ csr,
    int* __restrict__ elist, int* __restrict__ plist) {
  __shared__ int h[64], lbase[64];
  const int t = threadIdx.x;
  if (t < 64) h[t] = 0;
  __syncthreads();
  const int row = blockIdx.x * 256 + t;
  const int p  = pairid[row];
  const int ea = p / 7, rem = p % 7;
  const int eb = rem + (rem >= ea ? 1 : 0);
  const int op = atomicAdd(&h[p], 1);
  const int oa = atomicAdd(&h[56 + ea], 1);
  const int ob = atomicAdd(&h[56 + eb], 1);
  __syncthreads();
  if (t < 64) lbase[t] = h[t] ? atomicAdd(&csr[t], h[t]) : 0;
  __syncthreads();
  const int pp = lbase[p] + op;                   // plist position
  plist[pp] = row;
  elist[lbase[56 + ea] + oa] = (pp << 15) | (row << 1);
  elist[lbase[56 + eb] + ob] = (pp << 15) | (row << 1) | 1;
}

// ---------------------------------------------------------------------------
// K1: hidden GEMM, expert-grouped. Writes Hg in PLIST ORDER (index pp from
// the packed elist entry) so k2's A-tile read is sequential.
// ---------------------------------------------------------------------------
template <bool XB>
__global__ __launch_bounds__(256) void k1_hidden(
    const float* __restrict__ x, const unsigned short* __restrict__ xb,
    const unsigned short* __restrict__ w1bt, const float* __restrict__ b1,
    const float2* __restrict__ tval, const int* __restrict__ elist,
    const int* __restrict__ hist, const int* __restrict__ base,
    const int* __restrict__ meta, unsigned short* __restrict__ Hg) {
  const int b = blockIdx.x;
  if (b >= meta[0]) return;
  const int item = meta[2 + b];
  const int e = item >> 16, tile = item & 0xffff;
  const int start = tile * 64;
  const int nr = min(64, hist[56 + e] - start);

  __shared__ unsigned short As[64 * 64];
  __shared__ unsigned short Bs[128 * 64];
  __shared__ int rowl[64];

  const int t = threadIdx.x;
  if (t < 64) rowl[t] = elist[base[56 + e] + start + (t < nr ? t : 0)];
  __syncthreads();

  const int wid = t >> 6, l = t & 63;
  const int wr = wid >> 1, wc = wid & 1;
  const int lg = l >> 4,   ln = l & 15;

  f32x4 acc[2][4];
#pragma unroll
  for (int ms = 0; ms < 2; ++ms)
#pragma unroll
    for (int nf = 0; nf < 4; ++nf) acc[ms][nf] = (f32x4){0.f, 0.f, 0.f, 0.f};

  const int ai = t >> 2, aseg = t & 3;
  const int arow = (rowl[ai] >> 1) & 0x3FFF;
  const float* asrcf = x + (size_t)arow * IN_DIM + aseg * 16;
  const unsigned short* asrcb = xb + (size_t)arow * IN_DIM + aseg * 16;
  const int bn = t >> 1, bhf = t & 1;
  const unsigned short* bsrc =
      w1bt + ((size_t)e * HID + bn) * IN_DIM + bhf * 32;

  if constexpr (XB) {
    u32x4 areg[2], breg[4];
    {
      const u32x4* ap = (const u32x4*)(asrcb);
      areg[0] = ap[0]; areg[1] = ap[1];
      const u32x4* bp = (const u32x4*)(bsrc);
#pragma unroll
      for (int j = 0; j < 4; ++j) breg[j] = bp[j];
    }
    for (int ks = 0; ks < 16; ++ks) {
      *(u32x4*)&As[sw64(ai, aseg * 16)]     = areg[0];
      *(u32x4*)&As[sw64(ai, aseg * 16 + 8)] = areg[1];
#pragma unroll
      for (int j = 0; j < 4; ++j)
        *(u32x4*)&Bs[sw64(bn, bhf * 32 + j * 8)] = breg[j];
      __syncthreads();
      if (ks < 15) {
        const u32x4* ap = (const u32x4*)(asrcb + (ks + 1) * 64);
        areg[0] = ap[0]; areg[1] = ap[1];
        const u32x4* bp = (const u32x4*)(bsrc + (ks + 1) * 64);
#pragma unroll
        for (int j = 0; j < 4; ++j) breg[j] = bp[j];
      }
      bf16x8 af[2][2], bf[4][2];
#pragma unroll
      for (int ms = 0; ms < 2; ++ms)
#pragma unroll
        for (int kh = 0; kh < 2; ++kh)
          af[ms][kh] = *(const bf16x8*)&As[sw64(wr*32 + ms*16 + ln, kh*32 + lg*8)];
#pragma unroll
      for (int nf = 0; nf < 4; ++nf)
#pragma unroll
        for (int kh = 0; kh < 2; ++kh)
          bf[nf][kh] = *(const bf16x8*)&Bs[sw64(wc*64 + nf*16 + ln, kh*32 + lg*8)];
#pragma unroll
      for (int ms = 0; ms < 2; ++ms)
#pragma unroll
        for (int nf = 0; nf < 4; ++nf) {
          acc[ms][nf] = __builtin_amdgcn_mfma_f32_16x16x32_bf16(af[ms][0], bf[nf][0], acc[ms][nf], 0, 0, 0);
          acc[ms][nf] = __builtin_amdgcn_mfma_f32_16x16x32_bf16(af[ms][1], bf[nf][1], acc[ms][nf], 0, 0, 0);
        }
      __syncthreads();
    }
  } else {
    for (int ks = 0; ks < 16; ++ks) {
      {
        const float4 f0 = *(const float4*)(asrcf + ks * 64);
        const float4 f1 = *(const float4*)(asrcf + ks * 64 + 4);
        const float4 f2 = *(const float4*)(asrcf + ks * 64 + 8);
        const float4 f3 = *(const float4*)(asrcf + ks * 64 + 12);
        u16x8 u0, u1;
        u0[0]=f2bf(f0.x); u0[1]=f2bf(f0.y); u0[2]=f2bf(f0.z); u0[3]=f2bf(f0.w);
        u0[4]=f2bf(f1.x); u0[5]=f2bf(f1.y); u0[6]=f2bf(f1.z); u0[7]=f2bf(f1.w);
        u1[0]=f2bf(f2.x); u1[1]=f2bf(f2.y); u1[2]=f2bf(f2.z); u1[3]=f2bf(f2.w);
        u1[4]=f2bf(f3.x); u1[5]=f2bf(f3.y); u1[6]=f2bf(f3.z); u1[7]=f2bf(f3.w);
        *(u16x8*)&As[sw64(ai, aseg * 16)]     = u0;
        *(u16x8*)&As[sw64(ai, aseg * 16 + 8)] = u1;
      }
      {
        const u32x4* bp = (const u32x4*)(bsrc + ks * 64);
#pragma unroll
        for (int j = 0; j < 4; ++j)
          *(u32x4*)&Bs[sw64(bn, bhf * 32 + j * 8)] = bp[j];
      }
      __syncthreads();
      bf16x8 af[2][2], bf[4][2];
#pragma unroll
      for (int ms = 0; ms < 2; ++ms)
#pragma unroll
        for (int kh = 0; kh < 2; ++kh)
          af[ms][kh] = *(const bf16x8*)&As[sw64(wr*32 + ms*16 + ln, kh*32 + lg*8)];
#pragma unroll
      for (int nf = 0; nf < 4; ++nf)
#pragma unroll
        for (int kh = 0; kh < 2; ++kh)
          bf[nf][kh] = *(const bf16x8*)&Bs[sw64(wc*64 + nf*16 + ln, kh*32 + lg*8)];
#pragma unroll
      for (int ms = 0; ms < 2; ++ms)
#pragma unroll
        for (int nf = 0; nf < 4; ++nf) {
          acc[ms][nf] = __builtin_amdgcn_mfma_f32_16x16x32_bf16(af[ms][0], bf[nf][0], acc[ms][nf], 0, 0, 0);
          acc[ms][nf] = __builtin_amdgcn_mfma_f32_16x16x32_bf16(af[ms][1], bf[nf][1], acc[ms][nf], 0, 0, 0);
        }
      __syncthreads();
    }
  }

  float b1c[4];
#pragma unroll
  for (int nf = 0; nf < 4; ++nf) b1c[nf] = b1[e * HID + wc*64 + nf*16 + ln];

#pragma unroll
  for (int ms = 0; ms < 2; ++ms)
#pragma unroll
    for (int r = 0; r < 4; ++r) {
      const int li = wr*32 + ms*16 + lg*4 + r;
      if (li < nr) {
        const int packed = rowl[li];
        const int row  = (packed >> 1) & 0x3FFF;
        const int slot = packed & 1;
        const int pp   = ((unsigned)packed) >> 15;
        const float2 tv = tval[row];
        const float vv = slot ? tv.y : tv.x;
#pragma unroll
        for (int nf = 0; nf < 4; ++nf) {
          const float hh = fmaxf(acc[ms][nf][r] + b1c[nf], 0.f) * vv;
          Hg[((size_t)pp * 2 + slot) * HID + wc*64 + nf*16 + ln] = f2bf(hh);
        }
      }
    }
}

// ---------------------------------------------------------------------------
// K2: output GEMM, pair-grouped (r13 structure). Grid axes SWAPPED for XCD
// L2 locality: blockIdx.x = row-tile (312), blockIdx.y = c-chunk (8). Same-
// tile chunks are 312 apart in dispatch order and 312 % 8 == 0, so all 8
// land on the SAME XCD -> the shared 32 KB Ah region is fetched once per
// XCD-local L2 instead of 8 times across XCDs.
// ---------------------------------------------------------------------------
__global__ __launch_bounds__(256) void k2_out(
    const unsigned short* __restrict__ Hg, const unsigned short* __restrict__ w2bt,
    const float* __restrict__ b2, const float2* __restrict__ tval,
    const int* __restrict__ plist, const int* __restrict__ hist,
    const int* __restrict__ base, const int* __restrict__ meta,
    float* __restrict__ out) {
  const int b = blockIdx.x;
  if (b >= meta[1]) return;
  const int item = meta[2 + MAXW1 + b];
  const int p = item >> 16, rt = item & 0xffff;
  const int ea = p / 7, rem = p % 7;
  const int eb = rem + (rem >= ea ? 1 : 0);
  const int start = rt * 64;
  const int gpos = base[p] + start;          // plist-global row-tile start
  const int nr = min(64, hist[p] - start);
  const int c0 = blockIdx.y * 128;

  __shared__ unsigned short Ah[64 * 256];   // 32 KB, staged once (sequential)
  __shared__ unsigned short Bs[128 * 64];   // 16 KB, per-ks
  __shared__ int rowl[64];
  __shared__ float2 vals[64];

  const int t = threadIdx.x;
  if (t < 64) {
    const int r = plist[gpos + (t < nr ? t : 0)];
    rowl[t] = r;
    vals[t] = tval[r];
  }
  __syncthreads();

  // stage A: rows gpos..gpos+63 of plist-ordered Hg -> contiguous 32 KB
  {
    const int i = t >> 2, q = t & 3;
    const int srow = min(gpos + i, B_ROWS - 1);   // clamp tail padding
    const u32x4* src = (const u32x4*)(Hg + (size_t)srow * 256 + q * 64);
#pragma unroll
    for (int j = 0; j < 8; ++j)
      *(u32x4*)&Ah[sw256(i, q * 64 + j * 8)] = src[j];
  }

  const int wid = t >> 6, l = t & 63;
  const int wr = wid >> 1, wc = wid & 1;
  const int lg = l >> 4,   ln = l & 15;

  f32x4 acc[2][4];
#pragma unroll
  for (int ms = 0; ms < 2; ++ms)
#pragma unroll
    for (int nf = 0; nf < 4; ++nf) acc[ms][nf] = (f32x4){0.f, 0.f, 0.f, 0.f};

  const int bn = t >> 1, bhf = t & 1;
  u32x4 breg[4];
  {
    const u32x4* bp = (const u32x4*)(
        w2bt + ((size_t)ea * NCLS + c0 + bn) * HID + bhf * 32);
#pragma unroll
    for (int j = 0; j < 4; ++j) breg[j] = bp[j];
  }
#pragma unroll
  for (int ks = 0; ks < 4; ++ks) {
#pragma unroll
    for (int j = 0; j < 4; ++j)
      *(u32x4*)&Bs[sw64(bn, bhf * 32 + j * 8)] = breg[j];
    __syncthreads();
    if (ks < 3) {   // prefetch next ks; hides under ds_read+MFMA
      const int exn = (ks + 1 < 2) ? ea : eb;
      const int hbn = ((ks + 1) & 1) * 64;
      const u32x4* bp = (const u32x4*)(
          w2bt + ((size_t)exn * NCLS + c0 + bn) * HID + hbn + bhf * 32);
#pragma unroll
      for (int j = 0; j < 4; ++j) breg[j] = bp[j];
    }
    bf16x8 af[2][2], bf[4][2];
#pragma unroll
    for (int ms = 0; ms < 2; ++ms)
#pragma unroll
      for (int kh = 0; kh < 2; ++kh)
        af[ms][kh] = *(const bf16x8*)&Ah[sw256(wr*32 + ms*16 + ln, ks*64 + kh*32 + lg*8)];
#pragma unroll
    for (int nf = 0; nf < 4; ++nf)
#pragma unroll
      for (int kh = 0; kh < 2; ++kh)
        bf[nf][kh] = *(const bf16x8*)&Bs[sw64(wc*64 + nf*16 + ln, kh*32 + lg*8)];
#pragma unroll
    for (int ms = 0; ms < 2; ++ms)
#pragma unroll
      for (int nf = 0; nf < 4; ++nf) {
        acc[ms][nf] = __builtin_amdgcn_mfma_f32_16x16x32_bf16(af[ms][0], bf[nf][0], acc[ms][nf], 0, 0, 0);
        acc[ms][nf] = __builtin_amdgcn_mfma_f32_16x16x32_bf16(af[ms][1], bf[nf][1], acc[ms][nf], 0, 0, 0);
      }
    __syncthreads();
  }

  float b2a[4], b2b[4];
#pragma unroll
  for (int nf = 0; nf < 4; ++nf) {
    const int c = c0 + wc*64 + nf*16 + ln;
    b2a[nf] = b2[ea * NCLS + c];
    b2b[nf] = b2[eb * NCLS + c];
  }
#pragma unroll
  for (int ms = 0; ms < 2; ++ms)
#pragma unroll
    for (int r = 0; r < 4; ++r) {
      const int li = wr*32 + ms*16 + lg*4 + r;
      if (li < nr) {
        const int row = rowl[li];
        const float2 v = vals[li];
#pragma unroll
        for (int nf = 0; nf < 4; ++nf) {
          const int c = c0 + wc*64 + nf*16 + ln;
          out[(size_t)row * NCLS + c] = acc[ms][nf][r] + v.x * b2a[nf] + v.y * b2b[nf];
        }
      }
    }
}

extern "C" void kernel_launch(void* const* d_in, const int* in_sizes, int n_in,
                              void* d_out, int out_size, void* d_ws, size_t ws_size,
                              hipStream_t stream) {
  const float* x   = (const float*)d_in[0];
  const float* gw  = (const float*)d_in[1];
  const float* gb  = (const float*)d_in[2];
  const float* w1  = (const float*)d_in[3];
  const float* b1  = (const float*)d_in[4];
  const float* w2  = (const float*)d_in[5];
  const float* b2  = (const float*)d_in[6];
  float* out = (float*)d_out;

  // ws layout (bytes). Nothing needs pre-zeroing:
  //   hist 0..256 | base 256..512 | csr 512..768 | meta 768..4104 (pad 4352)
  //   partials 4352..20736 | psum 20736..21248 | pairid 21248..37632
  //   tval 37632..168704 | elist 168704..299776 | plist 299776..365312
  //   w1bt 365312..2462464 | w2bt 2462464..4559616 | Hg 4559616..12948224
  //   xb  12948224..46502656 (optional)
  char* ws = (char*)d_ws;
  int*            hist     = (int*)(ws);
  int*            base     = (int*)(ws + 256);
  int*            csr      = (int*)(ws + 512);
  int*            meta     = (int*)(ws + 768);
  int*            partials = (int*)(ws + 4352);
  float2*         psum     = (float2*)(ws + 20736);
  unsigned char*  pairid   = (unsigned char*)(ws + 21248);
  float2*         tval     = (float2*)(ws + 37632);
  int*            elist    = (int*)(ws + 168704);
  int*            plist    = (int*)(ws + 299776);
  unsigned short* w1bt     = (unsigned short*)(ws + 365312);
  unsigned short* w2bt     = (unsigned short*)(ws + 2462464);
  unsigned short* Hg       = (unsigned short*)(ws + 4559616);
  const bool use_xb = (ws_size >= (size_t)46502656);
  unsigned short* xb = use_xb ? (unsigned short*)(ws + 12948224) : nullptr;

  prep_kernel<<<GATE_BLOCKS + W1T_BLOCKS + W2T_BLOCKS, 256, 0, stream>>>(
      x, gw, gb, w1, w2, xb, w1bt, w2bt, tval, pairid);
  hist_part_kernel<<<B_ROWS / 256, 256, 0, stream>>>(pairid, tval, partials, psum);
  scan_kernel<<<1, 64, 0, stream>>>(partials, psum, hist, base, csr, meta, out);
  scatter_kernel<<<B_ROWS / 256, 256, 0, stream>>>(pairid, csr, elist, plist);

  if (use_xb)
    k1_hidden<true><<<MAXW1, 256, 0, stream>>>(x, xb, w1bt, b1, tval, elist,
                                               hist, base, meta, Hg);
  else
    k1_hidden<false><<<MAXW1, 256, 0, stream>>>(x, xb, w1bt, b1, tval, elist,
                                                hist, base, meta, Hg);
  k2_out<<<dim3(MAXW2, NCLS / 128), 256, 0, stream>>>(Hg, w2bt, b2, tval, plist,
                                                      hist, base, meta, out);
}

// Round 17
// 116.180 us; speedup vs baseline: 1.6127x; 1.0023x over previous
//
#include <hip/hip_runtime.h>

#define B_ROWS  16384
#define IN_DIM  1024
#define NEXP    8
#define HID     128
#define NCLS    1024
#define NPAIR   56
#define MAXW1   520   // max K1 work items: 32768/64 + 8
#define MAXW2   312   // max K2 work items: 16384/64 + 56

#define GATE_BLOCKS (B_ROWS / 8)                        // 2048
#define W1T_BLOCKS  (NEXP * (IN_DIM / 32) * (HID / 32)) // 1024
#define W2T_BLOCKS  (NEXP * (HID / 32) * (NCLS / 32))   // 1024

typedef __attribute__((ext_vector_type(8))) short bf16x8;
typedef __attribute__((ext_vector_type(4))) float f32x4;
typedef __attribute__((ext_vector_type(4))) unsigned int u32x4;
typedef __attribute__((ext_vector_type(8))) unsigned short u16x8;

__device__ __forceinline__ unsigned short f2bf(float f) {
  union { float f; unsigned u; } v; v.f = f;
  unsigned r = v.u + 0x7FFFu + ((v.u >> 16) & 1u);
  return (unsigned short)(r >> 16);
}

// XOR-swizzled LDS addressing (T2): linear rows, 8-short (16B) slots,
// slot ^= row&7.
__device__ __forceinline__ int sw64(int row, int sh) {   // 64-short rows
  return (row << 6) + ((((sh >> 3) ^ row) & 7) << 3) + (sh & 7);
}
__device__ __forceinline__ int sw256(int row, int sh) {  // 256-short rows
  return (row << 8) + ((((sh >> 3) ^ row) & 7) << 3) + (sh & 7) + ((sh >> 6) << 6);
}

// ---------------------------------------------------------------------------
// Fused prep: blocks [0,2048) gate+x->bf16; [2048,3072) w1 transpose;
// [3072,4096) w2 transpose.
// ---------------------------------------------------------------------------
__global__ __launch_bounds__(256) void prep_kernel(
    const float* __restrict__ x, const float* __restrict__ gw,
    const float* __restrict__ gb, const float* __restrict__ w1,
    const float* __restrict__ w2, unsigned short* __restrict__ xb,
    unsigned short* __restrict__ w1bt, unsigned short* __restrict__ w2bt,
    float2* __restrict__ tval, unsigned char* __restrict__ pairid) {
  __shared__ __attribute__((aligned(16))) unsigned char pmem[NEXP * IN_DIM * 4];
  const int bid = blockIdx.x;
  const int t = threadIdx.x;

  if (bid < GATE_BLOCKS) {
    float (*gws)[IN_DIM] = (float(*)[IN_DIM])pmem;   // 32 KB
#pragma unroll
    for (int kk = 0; kk < 4; ++kk) {
      const int k = kk * 256 + t;
      const float4 g0 = *(const float4*)(gw + k * NEXP);
      const float4 g1 = *(const float4*)(gw + k * NEXP + 4);
      gws[0][k] = g0.x; gws[1][k] = g0.y; gws[2][k] = g0.z; gws[3][k] = g0.w;
      gws[4][k] = g1.x; gws[5][k] = g1.y; gws[6][k] = g1.z; gws[7][k] = g1.w;
    }
    __syncthreads();

    const int wave = t >> 6, l = t & 63;
    const int r0 = bid * 8 + wave * 2;

    float4 xv0[4], xv1[4];
#pragma unroll
    for (int j = 0; j < 4; ++j) {
      xv0[j] = *(const float4*)(x + (size_t)r0 * IN_DIM + j * 256 + l * 4);
      xv1[j] = *(const float4*)(x + (size_t)(r0 + 1) * IN_DIM + j * 256 + l * 4);
    }

    if (xb) {
#pragma unroll
      for (int j = 0; j < 4; ++j) {
        uint2 p0, p1;
        p0.x = (unsigned)f2bf(xv0[j].x) | ((unsigned)f2bf(xv0[j].y) << 16);
        p0.y = (unsigned)f2bf(xv0[j].z) | ((unsigned)f2bf(xv0[j].w) << 16);
        p1.x = (unsigned)f2bf(xv1[j].x) | ((unsigned)f2bf(xv1[j].y) << 16);
        p1.y = (unsigned)f2bf(xv1[j].z) | ((unsigned)f2bf(xv1[j].w) << 16);
        *(uint2*)(xb + (size_t)r0 * IN_DIM + j * 256 + l * 4)       = p0;
        *(uint2*)(xb + (size_t)(r0 + 1) * IN_DIM + j * 256 + l * 4) = p1;
      }
    }

    float a0[NEXP], a1[NEXP];
#pragma unroll
    for (int e = 0; e < NEXP; ++e) { a0[e] = 0.f; a1[e] = 0.f; }
#pragma unroll
    for (int e = 0; e < NEXP; ++e) {
#pragma unroll
      for (int j = 0; j < 4; ++j) {
        const float4 g = *(const float4*)&gws[e][j * 256 + l * 4];
        a0[e] = fmaf(xv0[j].x, g.x, a0[e]); a0[e] = fmaf(xv0[j].y, g.y, a0[e]);
        a0[e] = fmaf(xv0[j].z, g.z, a0[e]); a0[e] = fmaf(xv0[j].w, g.w, a0[e]);
        a1[e] = fmaf(xv1[j].x, g.x, a1[e]); a1[e] = fmaf(xv1[j].y, g.y, a1[e]);
        a1[e] = fmaf(xv1[j].z, g.z, a1[e]); a1[e] = fmaf(xv1[j].w, g.w, a1[e]);
      }
    }
#pragma unroll
    for (int e = 0; e < NEXP; ++e) {
#pragma unroll
      for (int off = 32; off > 0; off >>= 1) {
        a0[e] += __shfl_xor(a0[e], off);
        a1[e] += __shfl_xor(a1[e], off);
      }
    }

    if (l == 0) {
#pragma unroll
      for (int rr = 0; rr < 2; ++rr) {
        const float* a = rr ? a1 : a0;
        float lg[NEXP];
#pragma unroll
        for (int e = 0; e < NEXP; ++e) lg[e] = a[e] + gb[e];
        float m = lg[0];
#pragma unroll
        for (int e = 1; e < NEXP; ++e) m = fmaxf(m, lg[e]);
        float p[NEXP], s = 0.f;
#pragma unroll
        for (int e = 0; e < NEXP; ++e) { p[e] = __expf(lg[e] - m); s += p[e]; }
        const float inv = 1.f / s;
        int   i0 = 0;  float v0 = p[0];
#pragma unroll
        for (int e = 1; e < NEXP; ++e) if (p[e] > v0) { v0 = p[e]; i0 = e; }
        int   i1 = -1; float v1 = -1.f;
#pragma unroll
        for (int e = 0; e < NEXP; ++e)
          if (e != i0 && p[e] > v1) { v1 = p[e]; i1 = e; }
        tval[r0 + rr] = make_float2(v0 * inv, v1 * inv);
        pairid[r0 + rr] = (unsigned char)(i0 * 7 + i1 - (i1 > i0 ? 1 : 0));
      }
    }
  } else {
    float (*tile)[33] = (float(*)[33])pmem;
    const float* src; unsigned short* dst;
    int R, C, r0, c0, e;
    if (bid < GATE_BLOCKS + W1T_BLOCKS) {
      const int b1 = bid - GATE_BLOCKS;
      e = b1 >> 7; const int rem = b1 & 127;
      R = IN_DIM; C = HID;
      c0 = (rem & 3) * 32; r0 = (rem >> 2) * 32;
      src = w1; dst = w1bt;
    } else {
      const int b2 = bid - GATE_BLOCKS - W1T_BLOCKS;
      e = b2 >> 7; const int rem = b2 & 127;
      R = HID; C = NCLS;
      c0 = (rem & 31) * 32; r0 = (rem >> 5) * 32;
      src = w2; dst = w2bt;
    }
    src += (size_t)e * R * C;
    dst += (size_t)e * R * C;
    const int tx = t & 31, ty = t >> 5;
#pragma unroll
    for (int i = ty; i < 32; i += 8)
      tile[i][tx] = src[(size_t)(r0 + i) * C + c0 + tx];
    __syncthreads();
#pragma unroll
    for (int i = ty; i < 32; i += 8)
      dst[(size_t)(c0 + i) * R + r0 + tx] = f2bf(tile[tx][i]);
  }
}

// ---------------------------------------------------------------------------
// Per-block partial histograms + partial tval sums (init-free).
// ---------------------------------------------------------------------------
__global__ __launch_bounds__(256) void hist_part_kernel(
    const unsigned char* __restrict__ pairid, const float2* __restrict__ tval,
    int* __restrict__ partials, float2* __restrict__ psum) {
  __shared__ int h[64];
  __shared__ float s0a[256], s1a[256];
  const int t = threadIdx.x;
  if (t < 64) h[t] = 0;
  __syncthreads();
  const int row = blockIdx.x * 256 + t;
  const int p  = pairid[row];
  const int ea = p / 7, rem = p % 7;
  const int eb = rem + (rem >= ea ? 1 : 0);
  atomicAdd(&h[p], 1);
  atomicAdd(&h[56 + ea], 1);
  atomicAdd(&h[56 + eb], 1);
  const float2 v = tval[row];
  s0a[t] = v.x; s1a[t] = v.y;
  __syncthreads();
#pragma unroll
  for (int s = 128; s > 0; s >>= 1) {
    if (t < s) { s0a[t] += s0a[t + s]; s1a[t] += s1a[t + s]; }
    __syncthreads();
  }
  if (t < 64) partials[blockIdx.x * 64 + t] = h[t];
  if (t == 0) psum[blockIdx.x] = make_float2(s0a[0], s1a[0]);
}

// ---------------------------------------------------------------------------
// Scan: sum partials -> hist; exclusive bases, cursors, exact work lists;
// also reduces psum and writes the gates_sum output rows.
// ---------------------------------------------------------------------------
__global__ void scan_kernel(const int* __restrict__ partials,
                            const float2* __restrict__ psum,
                            int* __restrict__ hist, int* __restrict__ base,
                            int* __restrict__ csr, int* __restrict__ meta,
                            float* __restrict__ out) {
  const int t = threadIdx.x;
  __shared__ float gg[2];
  if (t < 64) {
    int s = 0;
    for (int b = 0; b < B_ROWS / 256; ++b) s += partials[b * 64 + t];
    hist[t] = s;
  }
  if (t == 0) {
    float g0 = 0.f, g1 = 0.f;
    for (int b = 0; b < B_ROWS / 256; ++b) { g0 += psum[b].x; g1 += psum[b].y; }
    gg[0] = g0; gg[1] = g1;
  }
  __syncthreads();
  float* gout = out + (size_t)B_ROWS * NCLS;
  for (int c = t; c < NCLS; c += 64) {
    gout[c]        = gg[0];
    gout[NCLS + c] = gg[1];
  }
  if (t != 0) return;
  int accp = 0, acce = 0;
  for (int p = 0; p < NPAIR; ++p) { base[p] = accp; csr[p] = accp; accp += hist[p]; }
  for (int e = 0; e < NEXP; ++e) {
    base[56 + e] = acce; csr[56 + e] = acce; acce += hist[56 + e];
  }
  int n = 0;
  int* w1 = meta + 2;
  for (int e = 0; e < NEXP; ++e) {
    const int tiles = (hist[56 + e] + 63) >> 6;
    for (int i = 0; i < tiles; ++i) w1[n++] = (e << 16) | i;
  }
  meta[0] = n;
  n = 0;
  int* w2 = meta + 2 + MAXW1;
  for (int p = 0; p < NPAIR; ++p) {
    const int tiles = (hist[p] + 63) >> 6;
    for (int i = 0; i < tiles; ++i) w2[n++] = (p << 16) | i;
  }
  meta[1] = n;
}

// ---------------------------------------------------------------------------
// Scatter: per-block LDS histogram -> one aggregated atomic per bin per block.
// elist entry = (pp << 15) | (row << 1) | slot  (pp = plist position).
// ---------------------------------------------------------------------------
__global__ __launch_bounds__(256) void scatter_kernel(
    const unsigned char* __restrict__ pairid, int* __restrict__ csr,
    int* __restrict__ elist, int* __restrict__ plist) {
  __shared__ int h[64], lbase[64];
  const int t = threadIdx.x;
  if (t < 64) h[t] = 0;
  __syncthreads();
  const int row = blockIdx.x * 256 + t;
  const int p  = pairid[row];
  const int ea = p / 7, rem = p % 7;
  const int eb = rem + (rem >= ea ? 1 : 0);
  const int op = atomicAdd(&h[p], 1);
  const int oa = atomicAdd(&h[56 + ea], 1);
  const int ob = atomicAdd(&h[56 + eb], 1);
  __syncthreads();
  if (t < 64) lbase[t] = h[t] ? atomicAdd(&csr[t], h[t]) : 0;
  __syncthreads();
  const int pp = lbase[p] + op;                   // plist position
  plist[pp] = row;
  elist[lbase[56 + ea] + oa] = (pp << 15) | (row << 1);
  elist[lbase[56 + eb] + ob] = (pp << 15) | (row << 1) | 1;
}

// ---------------------------------------------------------------------------
// K1: hidden GEMM, expert-grouped. Writes Hg in PLIST ORDER (index pp from
// the packed elist entry) so k2's A-tile read is sequential.
// ---------------------------------------------------------------------------
template <bool XB>
__global__ __launch_bounds__(256) void k1_hidden(
    const float* __restrict__ x, const unsigned short* __restrict__ xb,
    const unsigned short* __restrict__ w1bt, const float* __restrict__ b1,
    const float2* __restrict__ tval, const int* __restrict__ elist,
    const int* __restrict__ hist, const int* __restrict__ base,
    const int* __restrict__ meta, unsigned short* __restrict__ Hg) {
  const int b = blockIdx.x;
  if (b >= meta[0]) return;
  const int item = meta[2 + b];
  const int e = item >> 16, tile = item & 0xffff;
  const int start = tile * 64;
  const int nr = min(64, hist[56 + e] - start);

  __shared__ unsigned short As[64 * 64];
  __shared__ unsigned short Bs[128 * 64];
  __shared__ int rowl[64];

  const int t = threadIdx.x;
  if (t < 64) rowl[t] = elist[base[56 + e] + start + (t < nr ? t : 0)];
  __syncthreads();

  const int wid = t >> 6, l = t & 63;
  const int wr = wid >> 1, wc = wid & 1;
  const int lg = l >> 4,   ln = l & 15;

  f32x4 acc[2][4];
#pragma unroll
  for (int ms = 0; ms < 2; ++ms)
#pragma unroll
    for (int nf = 0; nf < 4; ++nf) acc[ms][nf] = (f32x4){0.f, 0.f, 0.f, 0.f};

  const int ai = t >> 2, aseg = t & 3;
  const int arow = (rowl[ai] >> 1) & 0x3FFF;
  const float* asrcf = x + (size_t)arow * IN_DIM + aseg * 16;
  const unsigned short* asrcb = xb + (size_t)arow * IN_DIM + aseg * 16;
  const int bn = t >> 1, bhf = t & 1;
  const unsigned short* bsrc =
      w1bt + ((size_t)e * HID + bn) * IN_DIM + bhf * 32;

  if constexpr (XB) {
    u32x4 areg[2], breg[4];
    {
      const u32x4* ap = (const u32x4*)(asrcb);
      areg[0] = ap[0]; areg[1] = ap[1];
      const u32x4* bp = (const u32x4*)(bsrc);
#pragma unroll
      for (int j = 0; j < 4; ++j) breg[j] = bp[j];
    }
    for (int ks = 0; ks < 16; ++ks) {
      *(u32x4*)&As[sw64(ai, aseg * 16)]     = areg[0];
      *(u32x4*)&As[sw64(ai, aseg * 16 + 8)] = areg[1];
#pragma unroll
      for (int j = 0; j < 4; ++j)
        *(u32x4*)&Bs[sw64(bn, bhf * 32 + j * 8)] = breg[j];
      __syncthreads();
      if (ks < 15) {
        const u32x4* ap = (const u32x4*)(asrcb + (ks + 1) * 64);
        areg[0] = ap[0]; areg[1] = ap[1];
        const u32x4* bp = (const u32x4*)(bsrc + (ks + 1) * 64);
#pragma unroll
        for (int j = 0; j < 4; ++j) breg[j] = bp[j];
      }
      bf16x8 af[2][2], bf[4][2];
#pragma unroll
      for (int ms = 0; ms < 2; ++ms)
#pragma unroll
        for (int kh = 0; kh < 2; ++kh)
          af[ms][kh] = *(const bf16x8*)&As[sw64(wr*32 + ms*16 + ln, kh*32 + lg*8)];
#pragma unroll
      for (int nf = 0; nf < 4; ++nf)
#pragma unroll
        for (int kh = 0; kh < 2; ++kh)
          bf[nf][kh] = *(const bf16x8*)&Bs[sw64(wc*64 + nf*16 + ln, kh*32 + lg*8)];
#pragma unroll
      for (int ms = 0; ms < 2; ++ms)
#pragma unroll
        for (int nf = 0; nf < 4; ++nf) {
          acc[ms][nf] = __builtin_amdgcn_mfma_f32_16x16x32_bf16(af[ms][0], bf[nf][0], acc[ms][nf], 0, 0, 0);
          acc[ms][nf] = __builtin_amdgcn_mfma_f32_16x16x32_bf16(af[ms][1], bf[nf][1], acc[ms][nf], 0, 0, 0);
        }
      __syncthreads();
    }
  } else {
    for (int ks = 0; ks < 16; ++ks) {
      {
        const float4 f0 = *(const float4*)(asrcf + ks * 64);
        const float4 f1 = *(const float4*)(asrcf + ks * 64 + 4);
        const float4 f2 = *(const float4*)(asrcf + ks * 64 + 8);
        const float4 f3 = *(const float4*)(asrcf + ks * 64 + 12);
        u16x8 u0, u1;
        u0[0]=f2bf(f0.x); u0[1]=f2bf(f0.y); u0[2]=f2bf(f0.z); u0[3]=f2bf(f0.w);
        u0[4]=f2bf(f1.x); u0[5]=f2bf(f1.y); u0[6]=f2bf(f1.z); u0[7]=f2bf(f1.w);
        u1[0]=f2bf(f2.x); u1[1]=f2bf(f2.y); u1[2]=f2bf(f2.z); u1[3]=f2bf(f2.w);
        u1[4]=f2bf(f3.x); u1[5]=f2bf(f3.y); u1[6]=f2bf(f3.z); u1[7]=f2bf(f3.w);
        *(u16x8*)&As[sw64(ai, aseg * 16)]     = u0;
        *(u16x8*)&As[sw64(ai, aseg * 16 + 8)] = u1;
      }
      {
        const u32x4* bp = (const u32x4*)(bsrc + ks * 64);
#pragma unroll
        for (int j = 0; j < 4; ++j)
          *(u32x4*)&Bs[sw64(bn, bhf * 32 + j * 8)] = bp[j];
      }
      __syncthreads();
      bf16x8 af[2][2], bf[4][2];
#pragma unroll
      for (int ms = 0; ms < 2; ++ms)
#pragma unroll
        for (int kh = 0; kh < 2; ++kh)
          af[ms][kh] = *(const bf16x8*)&As[sw64(wr*32 + ms*16 + ln, kh*32 + lg*8)];
#pragma unroll
      for (int nf = 0; nf < 4; ++nf)
#pragma unroll
        for (int kh = 0; kh < 2; ++kh)
          bf[nf][kh] = *(const bf16x8*)&Bs[sw64(wc*64 + nf*16 + ln, kh*32 + lg*8)];
#pragma unroll
      for (int ms = 0; ms < 2; ++ms)
#pragma unroll
        for (int nf = 0; nf < 4; ++nf) {
          acc[ms][nf] = __builtin_amdgcn_mfma_f32_16x16x32_bf16(af[ms][0], bf[nf][0], acc[ms][nf], 0, 0, 0);
          acc[ms][nf] = __builtin_amdgcn_mfma_f32_16x16x32_bf16(af[ms][1], bf[nf][1], acc[ms][nf], 0, 0, 0);
        }
      __syncthreads();
    }
  }

  float b1c[4];
#pragma unroll
  for (int nf = 0; nf < 4; ++nf) b1c[nf] = b1[e * HID + wc*64 + nf*16 + ln];

#pragma unroll
  for (int ms = 0; ms < 2; ++ms)
#pragma unroll
    for (int r = 0; r < 4; ++r) {
      const int li = wr*32 + ms*16 + lg*4 + r;
      if (li < nr) {
        const int packed = rowl[li];
        const int row  = (packed >> 1) & 0x3FFF;
        const int slot = packed & 1;
        const int pp   = ((unsigned)packed) >> 15;
        const float2 tv = tval[row];
        const float vv = slot ? tv.y : tv.x;
#pragma unroll
        for (int nf = 0; nf < 4; ++nf) {
          const float hh = fmaxf(acc[ms][nf][r] + b1c[nf], 0.f) * vv;
          Hg[((size_t)pp * 2 + slot) * HID + wc*64 + nf*16 + ln] = f2bf(hh);
        }
      }
    }
}

// ---------------------------------------------------------------------------
// K2: output GEMM, pair-grouped. blockIdx.x = row-tile (XCD locality: same-
// tile blocks are 312 apart, 312 % 8 == 0 -> same XCD). blockIdx.y = c-pair;
// each block computes TWO 128-col chunks reusing the staged 32 KB Ah
// (Hg re-staging 8x -> 4x) with the r13/r16 register budget per chunk.
// ---------------------------------------------------------------------------
__global__ __launch_bounds__(256) void k2_out(
    const unsigned short* __restrict__ Hg, const unsigned short* __restrict__ w2bt,
    const float* __restrict__ b2, const float2* __restrict__ tval,
    const int* __restrict__ plist, const int* __restrict__ hist,
    const int* __restrict__ base, const int* __restrict__ meta,
    float* __restrict__ out) {
  const int b = blockIdx.x;
  if (b >= meta[1]) return;
  const int item = meta[2 + MAXW1 + b];
  const int p = item >> 16, rt = item & 0xffff;
  const int ea = p / 7, rem = p % 7;
  const int eb = rem + (rem >= ea ? 1 : 0);
  const int start = rt * 64;
  const int gpos = base[p] + start;          // plist-global row-tile start
  const int nr = min(64, hist[p] - start);
  const int c0base = blockIdx.y * 256;

  __shared__ unsigned short Ah[64 * 256];   // 32 KB, staged once (sequential)
  __shared__ unsigned short Bs[128 * 64];   // 16 KB, per-ks
  __shared__ int rowl[64];
  __shared__ float2 vals[64];

  const int t = threadIdx.x;
  if (t < 64) {
    const int r = plist[gpos + (t < nr ? t : 0)];
    rowl[t] = r;
    vals[t] = tval[r];
  }
  __syncthreads();

  // stage A: rows gpos..gpos+63 of plist-ordered Hg -> contiguous 32 KB
  {
    const int i = t >> 2, q = t & 3;
    const int srow = min(gpos + i, B_ROWS - 1);   // clamp tail padding
    const u32x4* src = (const u32x4*)(Hg + (size_t)srow * 256 + q * 64);
#pragma unroll
    for (int j = 0; j < 8; ++j)
      *(u32x4*)&Ah[sw256(i, q * 64 + j * 8)] = src[j];
  }

  const int wid = t >> 6, l = t & 63;
  const int wr = wid >> 1, wc = wid & 1;
  const int lg = l >> 4,   ln = l & 15;
  const int bn = t >> 1, bhf = t & 1;

#pragma unroll
  for (int ch2 = 0; ch2 < 2; ++ch2) {
    const int c0 = c0base + ch2 * 128;

    f32x4 acc[2][4];
#pragma unroll
    for (int ms = 0; ms < 2; ++ms)
#pragma unroll
      for (int nf = 0; nf < 4; ++nf) acc[ms][nf] = (f32x4){0.f, 0.f, 0.f, 0.f};

    u32x4 breg[4];
    {
      const u32x4* bp = (const u32x4*)(
          w2bt + ((size_t)ea * NCLS + c0 + bn) * HID + bhf * 32);
#pragma unroll
      for (int j = 0; j < 4; ++j) breg[j] = bp[j];
    }
#pragma unroll
    for (int ks = 0; ks < 4; ++ks) {
#pragma unroll
      for (int j = 0; j < 4; ++j)
        *(u32x4*)&Bs[sw64(bn, bhf * 32 + j * 8)] = breg[j];
      __syncthreads();
      if (ks < 3) {   // prefetch next ks; hides under ds_read+MFMA
        const int exn = (ks + 1 < 2) ? ea : eb;
        const int hbn = ((ks + 1) & 1) * 64;
        const u32x4* bp = (const u32x4*)(
            w2bt + ((size_t)exn * NCLS + c0 + bn) * HID + hbn + bhf * 32);
#pragma unroll
        for (int j = 0; j < 4; ++j) breg[j] = bp[j];
      }
      bf16x8 af[2][2], bf[4][2];
#pragma unroll
      for (int ms = 0; ms < 2; ++ms)
#pragma unroll
        for (int kh = 0; kh < 2; ++kh)
          af[ms][kh] = *(const bf16x8*)&Ah[sw256(wr*32 + ms*16 + ln, ks*64 + kh*32 + lg*8)];
#pragma unroll
      for (int nf = 0; nf < 4; ++nf)
#pragma unroll
        for (int kh = 0; kh < 2; ++kh)
          bf[nf][kh] = *(const bf16x8*)&Bs[sw64(wc*64 + nf*16 + ln, kh*32 + lg*8)];
#pragma unroll
      for (int ms = 0; ms < 2; ++ms)
#pragma unroll
        for (int nf = 0; nf < 4; ++nf) {
          acc[ms][nf] = __builtin_amdgcn_mfma_f32_16x16x32_bf16(af[ms][0], bf[nf][0], acc[ms][nf], 0, 0, 0);
          acc[ms][nf] = __builtin_amdgcn_mfma_f32_16x16x32_bf16(af[ms][1], bf[nf][1], acc[ms][nf], 0, 0, 0);
        }
      __syncthreads();
    }

    float b2a[4], b2b[4];
#pragma unroll
    for (int nf = 0; nf < 4; ++nf) {
      const int c = c0 + wc*64 + nf*16 + ln;
      b2a[nf] = b2[ea * NCLS + c];
      b2b[nf] = b2[eb * NCLS + c];
    }
#pragma unroll
    for (int ms = 0; ms < 2; ++ms)
#pragma unroll
      for (int r = 0; r < 4; ++r) {
        const int li = wr*32 + ms*16 + lg*4 + r;
        if (li < nr) {
          const int row = rowl[li];
          const float2 v = vals[li];
#pragma unroll
          for (int nf = 0; nf < 4; ++nf) {
            const int c = c0 + wc*64 + nf*16 + ln;
            out[(size_t)row * NCLS + c] = acc[ms][nf][r] + v.x * b2a[nf] + v.y * b2b[nf];
          }
        }
      }
  }
}

extern "C" void kernel_launch(void* const* d_in, const int* in_sizes, int n_in,
                              void* d_out, int out_size, void* d_ws, size_t ws_size,
                              hipStream_t stream) {
  const float* x   = (const float*)d_in[0];
  const float* gw  = (const float*)d_in[1];
  const float* gb  = (const float*)d_in[2];
  const float* w1  = (const float*)d_in[3];
  const float* b1  = (const float*)d_in[4];
  const float* w2  = (const float*)d_in[5];
  const float* b2  = (const float*)d_in[6];
  float* out = (float*)d_out;

  // ws layout (bytes). Nothing needs pre-zeroing:
  //   hist 0..256 | base 256..512 | csr 512..768 | meta 768..4104 (pad 4352)
  //   partials 4352..20736 | psum 20736..21248 | pairid 21248..37632
  //   tval 37632..168704 | elist 168704..299776 | plist 299776..365312
  //   w1bt 365312..2462464 | w2bt 2462464..4559616 | Hg 4559616..12948224
  //   xb  12948224..46502656 (optional)
  char* ws = (char*)d_ws;
  int*            hist     = (int*)(ws);
  int*            base     = (int*)(ws + 256);
  int*            csr      = (int*)(ws + 512);
  int*            meta     = (int*)(ws + 768);
  int*            partials = (int*)(ws + 4352);
  float2*         psum     = (float2*)(ws + 20736);
  unsigned char*  pairid   = (unsigned char*)(ws + 21248);
  float2*         tval     = (float2*)(ws + 37632);
  int*            elist    = (int*)(ws + 168704);
  int*            plist    = (int*)(ws + 299776);
  unsigned short* w1bt     = (unsigned short*)(ws + 365312);
  unsigned short* w2bt     = (unsigned short*)(ws + 2462464);
  unsigned short* Hg       = (unsigned short*)(ws + 4559616);
  const bool use_xb = (ws_size >= (size_t)46502656);
  unsigned short* xb = use_xb ? (unsigned short*)(ws + 12948224) : nullptr;

  prep_kernel<<<GATE_BLOCKS + W1T_BLOCKS + W2T_BLOCKS, 256, 0, stream>>>(
      x, gw, gb, w1, w2, xb, w1bt, w2bt, tval, pairid);
  hist_part_kernel<<<B_ROWS / 256, 256, 0, stream>>>(pairid, tval, partials, psum);
  scan_kernel<<<1, 64, 0, stream>>>(partials, psum, hist, base, csr, meta, out);
  scatter_kernel<<<B_ROWS / 256, 256, 0, stream>>>(pairid, csr, elist, plist);

  if (use_xb)
    k1_hidden<true><<<MAXW1, 256, 0, stream>>>(x, xb, w1bt, b1, tval, elist,
                                               hist, base, meta, Hg);
  else
    k1_hidden<false><<<MAXW1, 256, 0, stream>>>(x, xb, w1bt, b1, tval, elist,
                                                hist, base, meta, Hg);
  k2_out<<<dim3(MAXW2, NCLS / 256), 256, 0, stream>>>(Hg, w2bt, b2, tval, plist,
                                                      hist, base, meta, out);
}